// Round 1
// 310.506 us; speedup vs baseline: 1.0246x; 1.0246x over previous
//
#include <hip/hip_runtime.h>

// SiameseGNN round 20: agg depad + gemm2 fused into agg1.
//
// R19 evidence: k_agg1/k_agg2 = 46.5us each, VALUBusy 63%, HBM 37%,
// MfmaUtil 0 -- VALU-issue-bound on the gather loop.
//   fix 1 (depad): edge loop was 16-slot-burst padded: avg 32 slots for
//          ~19 real edges (maxd ~ max of two Poisson(16)). Replace with
//          fully-unrolled u<16 issue/consume loops + wave-uniform break at
//          2u >= mW: 2-slot granularity (~20 slots avg, -28% edge-loop
//          VALU+VMEM) and up-to-16-deep in-flight gathers (was 8).
//          Guards are SALU; h[u] indices stay compile-time (no scratch).
//   fix 2 (fuse): k_gemm2 deleted. agg1 stages its 8 bf16 rows in LDS
//          (1KB), one barrier, each wave MFMAs one 16-col tile of W2
//          (rows 8..15 zero-padded) and stores fp8 to Hs2. Kills the Ab
//          round-trip (25MB write + 25MB read) and one dispatch. Hs2
//          aliases temp (dead after csrb; 8MB >= 6.4MB+64) -- no ws
//          growth, batched path preserved. agg2 gathers from Hs2.
// Everything else unchanged from R19 (pre-shifted CSR, sentinel row,
// fp8, LDS-sort binA, bucket-major csr, batching, XCD swizzle).

#define TPB    256
#define CHUNK  128
#define SHIFT  7
#define KMAX   1024
#define CAP    2560
#define EPB    8192
#define CPAD   16      // cursorG stride (ints)

typedef __attribute__((ext_vector_type(8))) short short8;
typedef __attribute__((ext_vector_type(4))) float f32x4;
typedef __attribute__((ext_vector_type(2))) float float2v;

struct Ctx {
    const float* X; const int* esrc; const int* edst;
    unsigned int* temp; unsigned char* Hs2; unsigned char* Hs;
    unsigned int* csr; int* row_ptr; int* degA; float* dinv; int* cursorG;
    float* P; float* P2; float* outp;
};

__device__ __forceinline__ unsigned short f2bf(float x) {
    union { float f; unsigned int i; } c; c.f = x;
    unsigned int r = c.i + 0x7FFFu + ((c.i >> 16) & 1u);   // RNE
    return (unsigned short)(r >> 16);
}
__device__ __forceinline__ unsigned char f2fp8(float x) {
    int p = __builtin_amdgcn_cvt_pk_fp8_f32(x, x, 0, false);
    return (unsigned char)(p & 0xFF);
}
__device__ __forceinline__ float2v up8lo(unsigned int w) {
    return __builtin_amdgcn_cvt_pk_f32_fp8(w, false);
}
__device__ __forceinline__ float2v up8hi(unsigned int w) {
    return __builtin_amdgcn_cvt_pk_f32_fp8(w, true);
}

__global__ void k_prepW2(const float* __restrict__ W1, const float* __restrict__ W2,
                         unsigned short* __restrict__ Wt1, unsigned short* __restrict__ Wt2) {
    const float* W = blockIdx.x ? W2 : W1;
    unsigned short* Wt = blockIdx.x ? Wt2 : Wt1;
    for (int i = threadIdx.x; i < 64 * 64; i += 256) {
        int n = i >> 6, k = i & 63;
        Wt[i] = f2bf(W[k * 64 + n]);
    }
}

// zero cursors + zero the Hs sentinel row (row N; ws re-poisoned per call)
__global__ void k_zeroCur(Ctx c0, Ctx c1, int nb0, int K, int N) {
    int b = blockIdx.x; Ctx c = c0;
    if (b >= nb0) { c = c1; b -= nb0; }
    int i = b * blockDim.x + threadIdx.x;
    if (i < K) c.cursorG[i * CPAD] = 0;
    if (b == 0 && threadIdx.x < 64) c.Hs[(size_t)N * 64 + threadIdx.x] = 0;
}

// binA: LDS counting sort per block, burst segment writes. 1024 threads.
__global__ __launch_bounds__(1024) void k_binA(Ctx c0, Ctx c1, int nb0, int E, int K) {
    __shared__ int cnt[KMAX];
    __shared__ int ofs[KMAX];
    __shared__ int segBase[KMAX];
    __shared__ unsigned int sorted[EPB];
    __shared__ unsigned short bkt[EPB];
    int b = blockIdx.x; Ctx c = c0;
    if (b >= nb0) { c = c1; b -= nb0; }
    int tid = threadIdx.x;               // 0..1023 == KMAX
    cnt[tid] = 0;
    __syncthreads();
    int base = b * EPB;
    int tot = E - base; if (tot > EPB) tot = EPB;
#pragma unroll
    for (int k = 0; k < EPB / 1024; ++k) {
        int e = base + k * 1024 + tid;
        if (e < E) atomicAdd(&cnt[c.edst[e] >> SHIFT], 1);
    }
    __syncthreads();
    int v = cnt[tid];
    segBase[tid] = v;
    __syncthreads();
#pragma unroll
    for (int off = 1; off < 1024; off <<= 1) {
        int t = (tid >= off) ? segBase[tid - off] : 0;
        __syncthreads();
        segBase[tid] += t;
        __syncthreads();
    }
    ofs[tid] = segBase[tid] - v;
    __syncthreads();
    if (tid < K) {
        segBase[tid] = v ? atomicAdd(&c.cursorG[tid * CPAD], v) : 0;
    } else {
        segBase[tid] = 0;
    }
    cnt[tid] = 0;
    __syncthreads();
#pragma unroll
    for (int k = 0; k < EPB / 1024; ++k) {
        int e = base + k * 1024 + tid;
        if (e < E) {
            int d = c.edst[e];
            int bk = d >> SHIFT;
            int r = atomicAdd(&cnt[bk], 1);
            int p = ofs[bk] + r;
            sorted[p] = ((unsigned int)(d & (CHUNK - 1)) << 17) | (unsigned int)c.esrc[e];
            bkt[p] = (unsigned short)bk;
        }
    }
    __syncthreads();
    for (int p = tid; p < tot; p += 1024) {
        unsigned int vv = sorted[p];
        int bk = bkt[p];
        int pos = segBase[bk] + (p - ofs[bk]);
        if (pos < CAP) c.temp[(size_t)bk * CAP + pos] = vv;
    }
}

// Per-bucket LDS counting sort -> bucket-major csr slice (stride CAP) +
// row_ptr (beg) + deg + dinv. csr stores src<<6 (pre-shifted byte offset).
__global__ __launch_bounds__(256) void k_csrb(Ctx c0, Ctx c1, int nb0, int N) {
    __shared__ int deg[CHUNK];
    __shared__ int lofs[CHUNK];
    __shared__ int cur[CHUNK];
    int b = blockIdx.x; Ctx c = c0;
    if (b >= nb0) { c = c1; b -= nb0; }
    int tid = threadIdx.x;
    if (tid < CHUNK) deg[tid] = 0;
    __syncthreads();
    int cnt = c.cursorG[b * CPAD]; if (cnt > CAP) cnt = CAP;
    const size_t tb = (size_t)b * CAP;
    for (int i = tid; i < cnt; i += 256) atomicAdd(&deg[c.temp[tb + i] >> 17], 1);
    __syncthreads();
    if (tid < CHUNK) lofs[tid] = deg[tid];
    __syncthreads();
#pragma unroll
    for (int off = 1; off < CHUNK; off <<= 1) {
        int t = (tid < CHUNK && tid >= off) ? lofs[tid - off] : 0;
        __syncthreads();
        if (tid < CHUNK) lofs[tid] += t;
        __syncthreads();
    }
    int base = b * CAP;                  // bucket-major: no global scan needed
    if (tid < CHUNK) {
        int excl = lofs[tid] - deg[tid];
        lofs[tid] = excl;
        cur[tid] = 0;
        int node = b * CHUNK + tid;
        if (node < N) {
            c.row_ptr[node] = base + excl;
            c.degA[node] = deg[tid];
            c.dinv[node] = rsqrtf((float)deg[tid] + 1.0f);
        }
    }
    __syncthreads();
    for (int i = tid; i < cnt; i += 256) {
        unsigned int p = c.temp[tb + i];
        int dl = p >> 17;
        int rank = atomicAdd(&cur[dl], 1);
        c.csr[base + lofs[dl] + rank] = (p & 0x1FFFFu) << 6;   // src byte offset
    }
}

// Shared MFMA body: A-fragments provided; B from Wt; store fp8 Hs.
__device__ __forceinline__ void mfma_tail(short8 a0, short8 a1,
                                          const unsigned short* __restrict__ Wt,
                                          unsigned char* __restrict__ Hs,
                                          int row0, int r, int q, int N) {
    short8 bfrag[4][2];
#pragma unroll
    for (int ct = 0; ct < 4; ++ct)
#pragma unroll
        for (int kb = 0; kb < 2; ++kb)
            bfrag[ct][kb] = *(const short8*)(Wt + (ct * 16 + r) * 64 + q * 8 + 32 * kb);
    f32x4 acc[4];
#pragma unroll
    for (int ct = 0; ct < 4; ++ct) {
        acc[ct] = (f32x4){0.0f, 0.0f, 0.0f, 0.0f};
        acc[ct] = __builtin_amdgcn_mfma_f32_16x16x32_bf16(a0, bfrag[ct][0], acc[ct], 0, 0, 0);
        acc[ct] = __builtin_amdgcn_mfma_f32_16x16x32_bf16(a1, bfrag[ct][1], acc[ct], 0, 0, 0);
    }
#pragma unroll
    for (int reg = 0; reg < 4; ++reg) {
        int row = row0 + q * 4 + reg;
        if (row < N) {
            size_t base = (size_t)row * 64 + r;
#pragma unroll
            for (int ct = 0; ct < 4; ++ct)
                Hs[base + ct * 16] = f2fp8(acc[ct][reg]);
        }
    }
}

// GEMM1: fp32 X in, dinv folded into A-fragment conversion.
__global__ __launch_bounds__(256) void k_gemm1(Ctx c0, Ctx c1, int nb0,
                                               const unsigned short* __restrict__ Wt,
                                               int nTiles, int N) {
    int b = blockIdx.x; Ctx c = c0;
    if (b >= nb0) { c = c1; b -= nb0; }
    int wave = threadIdx.x >> 6, lane = threadIdx.x & 63;
    int tile = b * 4 + wave;
    if (tile >= nTiles) return;
    int r = lane & 15, q = lane >> 4;
    int row0 = tile * 16;
    int row = row0 + r;
    int rr = row < N ? row : N - 1;
    float d = c.dinv[rr];
    const float* xrow = c.X + (size_t)rr * 64 + q * 8;
    short8 a0, a1;
#pragma unroll
    for (int j = 0; j < 8; ++j) a0[j] = (short)f2bf(xrow[j] * d);
#pragma unroll
    for (int j = 0; j < 8; ++j) a1[j] = (short)f2bf(xrow[32 + j] * d);
    mfma_tail(a0, a1, Wt, c.Hs, row0, r, q, N);
}

// agg block mapping: XCD-partition swizzle (graph = (blockIdx>>2)&1) when
// swz, else linear split.
__device__ __forceinline__ void agg_map(int bi, int nb0, int swz,
                                        const Ctx& c0, const Ctx& c1,
                                        Ctx& c, int& b) {
    if (swz) {
        int graph = (bi >> 2) & 1;
        b = ((bi >> 3) << 2) | (bi & 3);
        c = graph ? c1 : c0;
    } else {
        b = bi; c = c0;
        if (b >= nb0) { c = c1; b -= nb0; }
    }
}

// 2 nodes per wave; per half: 2 groups x 16 lanes, lane s covers fp8
// channels 4s..4s+3. csr holds src<<6; gather offset = su | (s*4).
// R20: unrolled u<16 issue/consume with wave-uniform break at 2u >= mW:
// 2-slot padding granularity (was 16) + up-to-16-deep load pipeline.
// Invalid slots -> sentinel N<<6 (zeros).
__device__ __forceinline__ void agg_node2(const unsigned char* __restrict__ Hs,
                                          const unsigned int* __restrict__ csr,
                                          int beg, int deg, int maxd, int lane,
                                          unsigned int sent, float2v* acc) {
    int hbase = lane & 32;
    int hl = lane & 31;
    int g = (lane >> 4) & 1;
    unsigned int s4 = (unsigned int)((lane & 15) * 4);
    for (int base = 0; base < maxd; base += 32) {
        unsigned int idx = (base + hl < deg) ? csr[beg + base + hl] : sent;
        int mW = maxd - base; if (mW > 32) mW = 32;   // wave-uniform
        unsigned int h[16];
#pragma unroll
        for (int u = 0; u < 16; ++u) {                // issue phase
            if (2 * u >= mW) break;                   // SALU, wave-uniform
            unsigned int su = (unsigned int)__shfl((int)idx, hbase + 2 * u + g, 64);
            h[u] = *(const unsigned int*)(Hs + (su | s4));   // saddr + voffset
        }
#pragma unroll
        for (int u = 0; u < 16; ++u) {                // consume phase
            if (2 * u >= mW) break;
            acc[0] += up8lo(h[u]); acc[1] += up8hi(h[u]);    // sentinel adds 0
        }
    }
    // merge the half's 2 groups (bit 4); does not cross halves
#pragma unroll
    for (int k = 0; k < 2; ++k) {
        float2v o;
        o.x = __shfl_xor(acc[k].x, 16, 64); o.y = __shfl_xor(acc[k].y, 16, 64);
        acc[k] += o;
    }
}

// layer-1 + fused GEMM2: v = dinv * relu(b + dinv * agg); rows staged in
// LDS as bf16, each wave MFMAs one 16-col tile of W2 (rows 8..15 zero),
// stores fp8 Hs2. Hs2 sentinel row N zeroed here (aliases temp).
__global__ __launch_bounds__(256) void k_agg1(Ctx c0, Ctx c1, int nb0, int swz,
                                              const float* __restrict__ bias,
                                              const unsigned short* __restrict__ Wt2,
                                              int n) {
    __shared__ unsigned short As[8][64];
    Ctx c; int b;
    agg_map(blockIdx.x, nb0, swz, c0, c1, c, b);
    int wave = threadIdx.x >> 6, lane = threadIdx.x & 63;
    int h = lane >> 5;
    int node = b * 8 + wave * 2 + h;
    int nd = node < n ? node : 0;
    int beg = c.row_ptr[nd];
    int deg = (node < n) ? c.degA[nd] : 0;
    int od = __shfl_xor(deg, 32, 64);
    int maxd = deg > od ? deg : od;      // wave-uniform
    if (b == 0 && threadIdx.x < 64) c.Hs2[(size_t)n * 64 + threadIdx.x] = 0;
    float2v acc[2] = {{0.f, 0.f}, {0.f, 0.f}};
    agg_node2(c.Hs, c.csr, beg, deg, maxd, lane, (unsigned int)n << 6, acc);
    if (((lane >> 4) & 1) == 0) {
        int s = lane & 15;
        ushort4 o = {0, 0, 0, 0};
        if (node < n) {
            unsigned int hv = *(const unsigned int*)(c.Hs + (size_t)node * 64 + s * 4);
            float2v h0 = up8lo(hv), h1 = up8hi(hv);
            float4 bb = *(const float4*)(bias + s * 4);
            float d = c.dinv[node];
            o.x = f2bf(fmaxf(bb.x + d * (acc[0].x + h0.x), 0.0f) * d);
            o.y = f2bf(fmaxf(bb.y + d * (acc[0].y + h0.y), 0.0f) * d);
            o.z = f2bf(fmaxf(bb.z + d * (acc[1].x + h1.x), 0.0f) * d);
            o.w = f2bf(fmaxf(bb.w + d * (acc[1].y + h1.y), 0.0f) * d);
        }
        *(ushort4*)(&As[wave * 2 + h][s * 4]) = o;
    }
    __syncthreads();
    // fused GEMM2: wave handles col-tile ct = wave; A rows 8..15 are zero.
    {
        int r = lane & 15, q = lane >> 4;
        short8 a0 = {}, a1 = {};
        if (r < 8) {
            a0 = *(const short8*)(&As[r][q * 8]);
            a1 = *(const short8*)(&As[r][q * 8 + 32]);
        }
        const unsigned short* wp = Wt2 + (wave * 16 + r) * 64 + q * 8;
        short8 b0 = *(const short8*)(wp);
        short8 b1 = *(const short8*)(wp + 32);
        f32x4 acc2 = {0.0f, 0.0f, 0.0f, 0.0f};
        acc2 = __builtin_amdgcn_mfma_f32_16x16x32_bf16(a0, b0, acc2, 0, 0, 0);
        acc2 = __builtin_amdgcn_mfma_f32_16x16x32_bf16(a1, b1, acc2, 0, 0, 0);
#pragma unroll
        for (int reg = 0; reg < 4; ++reg) {
            int l = q * 4 + reg;                     // local row 0..15
            int row = b * 8 + l;
            if (l < 8 && row < n)
                c.Hs2[(size_t)row * 64 + wave * 16 + r] = f2fp8(acc2[reg]);
        }
    }
}

// layer-2: block-reduce 8 relu'd rows -> P[block, f] (gathers from Hs2)
__global__ __launch_bounds__(256) void k_agg2(Ctx c0, Ctx c1, int nb0, int swz,
                                              const float* __restrict__ bias, int n) {
    __shared__ float red[8 * 64];
    Ctx c; int b;
    agg_map(blockIdx.x, nb0, swz, c0, c1, c, b);
    int wave = threadIdx.x >> 6, lane = threadIdx.x & 63;
    int h = lane >> 5;
    int node = b * 8 + wave * 2 + h;
    int nd = node < n ? node : 0;
    int beg = c.row_ptr[nd];
    int deg = (node < n) ? c.degA[nd] : 0;
    int od = __shfl_xor(deg, 32, 64);
    int maxd = deg > od ? deg : od;
    float2v acc[2] = {{0.f, 0.f}, {0.f, 0.f}};
    agg_node2(c.Hs2, c.csr, beg, deg, maxd, lane, (unsigned int)n << 6, acc);
    if (((lane >> 4) & 1) == 0) {
        int s = lane & 15;
        float4 v = {0.f, 0.f, 0.f, 0.f};
        if (node < n) {
            unsigned int hv = *(const unsigned int*)(c.Hs2 + (size_t)node * 64 + s * 4);
            float2v h0 = up8lo(hv), h1 = up8hi(hv);
            float4 bb = *(const float4*)(bias + s * 4);
            float d = c.dinv[node];
            v.x = fmaxf(bb.x + d * (acc[0].x + h0.x), 0.0f);
            v.y = fmaxf(bb.y + d * (acc[0].y + h0.y), 0.0f);
            v.z = fmaxf(bb.z + d * (acc[1].x + h1.x), 0.0f);
            v.w = fmaxf(bb.w + d * (acc[1].y + h1.y), 0.0f);
        }
        *(float4*)(&red[(wave * 2 + h) * 64 + s * 4]) = v;
    }
    __syncthreads();
    if (threadIdx.x < 64) {
        float acc8 = 0.0f;
#pragma unroll
        for (int r = 0; r < 8; ++r) acc8 += red[r * 64 + threadIdx.x];
        c.P[(size_t)b * 64 + threadIdx.x] = acc8;
    }
}

// colsum -> per-block partials in P2 (no atomics, no zero pass)
__global__ void k_colsum(Ctx c0, Ctx c1, int nb0, int rows) {
    int b = blockIdx.x; Ctx c = c0;
    if (b >= nb0) { c = c1; b -= nb0; }
    int f = threadIdx.x;  // 64
    float acc = 0.0f;
    for (int r = b; r < rows; r += nb0) acc += c.P[(size_t)r * 64 + f];
    c.P2[b * 64 + f] = acc;
}

// single-wave FC: reduce 256 partial rows, then out = fcb + (S/n) @ fcw^T
__global__ void k_fc(Ctx c0, Ctx c1, const float* __restrict__ fcw,
                     const float* __restrict__ fcb, int n) {
    Ctx c = blockIdx.x ? c1 : c0;
    __shared__ float S[64];
    int j = threadIdx.x;  // 64
    float s = 0.0f;
    for (int r = 0; r < 256; ++r) s += c.P2[r * 64 + j];
    S[j] = s;
    __syncthreads();
    float inv = 1.0f / (float)n;
    float acc = fcb[j];
#pragma unroll
    for (int k = 0; k < 64; ++k) acc += (S[k] * inv) * fcw[j * 64 + k];
    c.outp[j] = acc;
}

extern "C" void kernel_launch(void* const* d_in, const int* in_sizes, int n_in,
                              void* d_out, int out_size, void* d_ws, size_t ws_size,
                              hipStream_t stream) {
    const float* x[2]  = {(const float*)d_in[0], (const float*)d_in[1]};
    const int*   ei[2] = {(const int*)d_in[2], (const int*)d_in[3]};
    const float* W1  = (const float*)d_in[4];
    const float* b1  = (const float*)d_in[5];
    const float* W2  = (const float*)d_in[6];
    const float* b2  = (const float*)d_in[7];
    const float* fcw = (const float*)d_in[8];
    const float* fcb = (const float*)d_in[9];
    float* out = (float*)d_out;

    const int N  = in_sizes[0] / 64;
    const int E  = in_sizes[2] / 2;
    const int NF = N * 64;
    const int K  = (N + CHUNK - 1) / CHUNK;     // 782 buckets
    const int gGm = (N + 7) / 8;                // aggregate blocks (8 nodes each)
    const int nTiles = (N + 15) / 16;
    const int gMf = (nTiles + 3) / 4;
    const int gBin = (E + EPB - 1) / EPB;
    const int gK  = (K + TPB - 1) / TPB;

    auto al = [](size_t x) { return (x + 127) & ~(size_t)127; };
    size_t tempB = (size_t)K * CAP * 4;
    size_t hs2B  = (size_t)NF + 64;                    // fp8 + sentinel row N
    size_t szRegion = al(tempB > hs2B ? tempB : hs2B); // Hs2 aliases temp
    size_t szHs  = al((size_t)NF + 64);                // fp8 + sentinel row N
    size_t szCsr = al((size_t)K * CAP * 4);            // bucket-major, stride CAP
    size_t szRp  = al((size_t)N * 4);                  // beg only
    size_t szDeg = al((size_t)N * 4);
    size_t szDi  = al((size_t)N * 4);
    size_t szCu  = al((size_t)K * CPAD * 4);           // padded cursors
    size_t szP   = al((size_t)gGm * 64 * 4);
    size_t szP2  = al((size_t)256 * 64 * 4);
    size_t setB  = szRegion + szHs + szCsr + szRp + szDeg + szDi + szCu + szP + szP2;
    size_t wtB   = 2 * al(64 * 64 * 2);
    bool batched = ws_size >= wtB + 2 * setB;

    char* base = (char*)d_ws;
    unsigned short* Wt1 = (unsigned short*)base;
    unsigned short* Wt2 = (unsigned short*)(base + al(64 * 64 * 2));

    auto mkctx = [&](int g, char* p) {
        Ctx c;
        c.X = x[g]; c.esrc = ei[g]; c.edst = ei[g] + E;
        c.temp = (unsigned int*)p; c.Hs2 = (unsigned char*)p; p += szRegion;
        c.Hs = (unsigned char*)p; p += szHs;
        c.csr = (unsigned int*)p; p += szCsr;
        c.row_ptr = (int*)p; p += szRp;
        c.degA = (int*)p; p += szDeg;
        c.dinv = (float*)p; p += szDi;
        c.cursorG = (int*)p; p += szCu;
        c.P = (float*)p; p += szP;
        c.P2 = (float*)p;
        c.outp = out + g * 64;
        return c;
    };
    char* set0 = base + wtB;
    Ctx c0 = mkctx(0, set0);
    Ctx c1 = mkctx(1, batched ? set0 + setB : set0);   // fallback: shares set0

    k_prepW2<<<2, 256, 0, stream>>>(W1, W2, Wt1, Wt2);

    auto pipe = [&](Ctx A, Ctx B, int mult) {
        int swz = (mult == 2 && (gGm & 3) == 0) ? 1 : 0;
        k_zeroCur<<<mult * gK, TPB, 0, stream>>>(A, B, gK, K, N);
        k_binA<<<mult * gBin, 1024, 0, stream>>>(A, B, gBin, E, K);
        k_csrb<<<mult * K, 256, 0, stream>>>(A, B, K, N);
        k_gemm1<<<mult * gMf, 256, 0, stream>>>(A, B, gMf, Wt1, nTiles, N);
        k_agg1<<<mult * gGm, 256, 0, stream>>>(A, B, gGm, swz, b1, Wt2, N);
        k_agg2<<<mult * gGm, 256, 0, stream>>>(A, B, gGm, swz, b2, N);
        k_colsum<<<mult * 256, 64, 0, stream>>>(A, B, 256, gGm);
        k_fc<<<mult, 64, 0, stream>>>(A, B, fcw, fcb, N);
    };

    if (batched) {
        pipe(c0, c1, 2);
    } else {
        pipe(c0, c0, 1);   // sequential, shared buffer set
        pipe(c1, c1, 1);
    }
}

// Round 2
// 304.524 us; speedup vs baseline: 1.0447x; 1.0196x over previous
//
#include <hip/hip_runtime.h>

// SiameseGNN round 21: scalar-guarded depad + swizzled fused-GEMM2 LDS.
//
// R20 evidence: k_agg1 46.5 -> 67.2us, VALU busy-time +45%, bank-conflict
// 0 -> 800K. Diagnosis: the u<16 break guards compare against mW held in
// a VGPR (derived from shfl_xor'd deg) -- compiler can't prove uniformity,
// so every 2-slot guard became divergent exec-mask control flow (v_cmp +
// s_and_saveexec per iteration) around a convergent __shfl, inflating VALU
// and fracturing the load pipeline. Also As[r][q*8] MFMA read = 16-way
// LDS bank conflict.
//   fix 1: maxd -> readfirstlane (provably wave-uniform: max of both
//          halves via shfl_xor(32)). All burst limits become SGPR ->
//          s_cmp/s_cbranch, zero exec churn, straight-line load batches.
//   fix 2: two 8-deep bursts (R19-proven VGPR shape) with scalar 2-slot
//          early-outs inside each: depad granularity 2, <=8 loads live.
//   fix 3: As XOR-swizzle at 16B granularity (col ^ ((row&7)<<3)), both
//          write and MFMA read sides: 16-way -> 2-way conflicts.
// Fusion of gemm2 into agg1 kept (WRITE_SIZE halved as predicted in R20).
// Everything else unchanged (pre-shifted CSR, sentinel row, fp8, LDS-sort
// binA, bucket-major csr, batching, XCD swizzle).

#define TPB    256
#define CHUNK  128
#define SHIFT  7
#define KMAX   1024
#define CAP    2560
#define EPB    8192
#define CPAD   16      // cursorG stride (ints)

typedef __attribute__((ext_vector_type(8))) short short8;
typedef __attribute__((ext_vector_type(4))) float f32x4;
typedef __attribute__((ext_vector_type(2))) float float2v;

struct Ctx {
    const float* X; const int* esrc; const int* edst;
    unsigned int* temp; unsigned char* Hs2; unsigned char* Hs;
    unsigned int* csr; int* row_ptr; int* degA; float* dinv; int* cursorG;
    float* P; float* P2; float* outp;
};

__device__ __forceinline__ unsigned short f2bf(float x) {
    union { float f; unsigned int i; } c; c.f = x;
    unsigned int r = c.i + 0x7FFFu + ((c.i >> 16) & 1u);   // RNE
    return (unsigned short)(r >> 16);
}
__device__ __forceinline__ unsigned char f2fp8(float x) {
    int p = __builtin_amdgcn_cvt_pk_fp8_f32(x, x, 0, false);
    return (unsigned char)(p & 0xFF);
}
__device__ __forceinline__ float2v up8lo(unsigned int w) {
    return __builtin_amdgcn_cvt_pk_f32_fp8(w, false);
}
__device__ __forceinline__ float2v up8hi(unsigned int w) {
    return __builtin_amdgcn_cvt_pk_f32_fp8(w, true);
}

__global__ void k_prepW2(const float* __restrict__ W1, const float* __restrict__ W2,
                         unsigned short* __restrict__ Wt1, unsigned short* __restrict__ Wt2) {
    const float* W = blockIdx.x ? W2 : W1;
    unsigned short* Wt = blockIdx.x ? Wt2 : Wt1;
    for (int i = threadIdx.x; i < 64 * 64; i += 256) {
        int n = i >> 6, k = i & 63;
        Wt[i] = f2bf(W[k * 64 + n]);
    }
}

// zero cursors + zero the Hs sentinel row (row N; ws re-poisoned per call)
__global__ void k_zeroCur(Ctx c0, Ctx c1, int nb0, int K, int N) {
    int b = blockIdx.x; Ctx c = c0;
    if (b >= nb0) { c = c1; b -= nb0; }
    int i = b * blockDim.x + threadIdx.x;
    if (i < K) c.cursorG[i * CPAD] = 0;
    if (b == 0 && threadIdx.x < 64) c.Hs[(size_t)N * 64 + threadIdx.x] = 0;
}

// binA: LDS counting sort per block, burst segment writes. 1024 threads.
__global__ __launch_bounds__(1024) void k_binA(Ctx c0, Ctx c1, int nb0, int E, int K) {
    __shared__ int cnt[KMAX];
    __shared__ int ofs[KMAX];
    __shared__ int segBase[KMAX];
    __shared__ unsigned int sorted[EPB];
    __shared__ unsigned short bkt[EPB];
    int b = blockIdx.x; Ctx c = c0;
    if (b >= nb0) { c = c1; b -= nb0; }
    int tid = threadIdx.x;               // 0..1023 == KMAX
    cnt[tid] = 0;
    __syncthreads();
    int base = b * EPB;
    int tot = E - base; if (tot > EPB) tot = EPB;
#pragma unroll
    for (int k = 0; k < EPB / 1024; ++k) {
        int e = base + k * 1024 + tid;
        if (e < E) atomicAdd(&cnt[c.edst[e] >> SHIFT], 1);
    }
    __syncthreads();
    int v = cnt[tid];
    segBase[tid] = v;
    __syncthreads();
#pragma unroll
    for (int off = 1; off < 1024; off <<= 1) {
        int t = (tid >= off) ? segBase[tid - off] : 0;
        __syncthreads();
        segBase[tid] += t;
        __syncthreads();
    }
    ofs[tid] = segBase[tid] - v;
    __syncthreads();
    if (tid < K) {
        segBase[tid] = v ? atomicAdd(&c.cursorG[tid * CPAD], v) : 0;
    } else {
        segBase[tid] = 0;
    }
    cnt[tid] = 0;
    __syncthreads();
#pragma unroll
    for (int k = 0; k < EPB / 1024; ++k) {
        int e = base + k * 1024 + tid;
        if (e < E) {
            int d = c.edst[e];
            int bk = d >> SHIFT;
            int r = atomicAdd(&cnt[bk], 1);
            int p = ofs[bk] + r;
            sorted[p] = ((unsigned int)(d & (CHUNK - 1)) << 17) | (unsigned int)c.esrc[e];
            bkt[p] = (unsigned short)bk;
        }
    }
    __syncthreads();
    for (int p = tid; p < tot; p += 1024) {
        unsigned int vv = sorted[p];
        int bk = bkt[p];
        int pos = segBase[bk] + (p - ofs[bk]);
        if (pos < CAP) c.temp[(size_t)bk * CAP + pos] = vv;
    }
}

// Per-bucket LDS counting sort -> bucket-major csr slice (stride CAP) +
// row_ptr (beg) + deg + dinv. csr stores src<<6 (pre-shifted byte offset).
__global__ __launch_bounds__(256) void k_csrb(Ctx c0, Ctx c1, int nb0, int N) {
    __shared__ int deg[CHUNK];
    __shared__ int lofs[CHUNK];
    __shared__ int cur[CHUNK];
    int b = blockIdx.x; Ctx c = c0;
    if (b >= nb0) { c = c1; b -= nb0; }
    int tid = threadIdx.x;
    if (tid < CHUNK) deg[tid] = 0;
    __syncthreads();
    int cnt = c.cursorG[b * CPAD]; if (cnt > CAP) cnt = CAP;
    const size_t tb = (size_t)b * CAP;
    for (int i = tid; i < cnt; i += 256) atomicAdd(&deg[c.temp[tb + i] >> 17], 1);
    __syncthreads();
    if (tid < CHUNK) lofs[tid] = deg[tid];
    __syncthreads();
#pragma unroll
    for (int off = 1; off < CHUNK; off <<= 1) {
        int t = (tid < CHUNK && tid >= off) ? lofs[tid - off] : 0;
        __syncthreads();
        if (tid < CHUNK) lofs[tid] += t;
        __syncthreads();
    }
    int base = b * CAP;                  // bucket-major: no global scan needed
    if (tid < CHUNK) {
        int excl = lofs[tid] - deg[tid];
        lofs[tid] = excl;
        cur[tid] = 0;
        int node = b * CHUNK + tid;
        if (node < N) {
            c.row_ptr[node] = base + excl;
            c.degA[node] = deg[tid];
            c.dinv[node] = rsqrtf((float)deg[tid] + 1.0f);
        }
    }
    __syncthreads();
    for (int i = tid; i < cnt; i += 256) {
        unsigned int p = c.temp[tb + i];
        int dl = p >> 17;
        int rank = atomicAdd(&cur[dl], 1);
        c.csr[base + lofs[dl] + rank] = (p & 0x1FFFFu) << 6;   // src byte offset
    }
}

// Shared MFMA body: A-fragments provided; B from Wt; store fp8 Hs.
__device__ __forceinline__ void mfma_tail(short8 a0, short8 a1,
                                          const unsigned short* __restrict__ Wt,
                                          unsigned char* __restrict__ Hs,
                                          int row0, int r, int q, int N) {
    short8 bfrag[4][2];
#pragma unroll
    for (int ct = 0; ct < 4; ++ct)
#pragma unroll
        for (int kb = 0; kb < 2; ++kb)
            bfrag[ct][kb] = *(const short8*)(Wt + (ct * 16 + r) * 64 + q * 8 + 32 * kb);
    f32x4 acc[4];
#pragma unroll
    for (int ct = 0; ct < 4; ++ct) {
        acc[ct] = (f32x4){0.0f, 0.0f, 0.0f, 0.0f};
        acc[ct] = __builtin_amdgcn_mfma_f32_16x16x32_bf16(a0, bfrag[ct][0], acc[ct], 0, 0, 0);
        acc[ct] = __builtin_amdgcn_mfma_f32_16x16x32_bf16(a1, bfrag[ct][1], acc[ct], 0, 0, 0);
    }
#pragma unroll
    for (int reg = 0; reg < 4; ++reg) {
        int row = row0 + q * 4 + reg;
        if (row < N) {
            size_t base = (size_t)row * 64 + r;
#pragma unroll
            for (int ct = 0; ct < 4; ++ct)
                Hs[base + ct * 16] = f2fp8(acc[ct][reg]);
        }
    }
}

// GEMM1: fp32 X in, dinv folded into A-fragment conversion.
__global__ __launch_bounds__(256) void k_gemm1(Ctx c0, Ctx c1, int nb0,
                                               const unsigned short* __restrict__ Wt,
                                               int nTiles, int N) {
    int b = blockIdx.x; Ctx c = c0;
    if (b >= nb0) { c = c1; b -= nb0; }
    int wave = threadIdx.x >> 6, lane = threadIdx.x & 63;
    int tile = b * 4 + wave;
    if (tile >= nTiles) return;
    int r = lane & 15, q = lane >> 4;
    int row0 = tile * 16;
    int row = row0 + r;
    int rr = row < N ? row : N - 1;
    float d = c.dinv[rr];
    const float* xrow = c.X + (size_t)rr * 64 + q * 8;
    short8 a0, a1;
#pragma unroll
    for (int j = 0; j < 8; ++j) a0[j] = (short)f2bf(xrow[j] * d);
#pragma unroll
    for (int j = 0; j < 8; ++j) a1[j] = (short)f2bf(xrow[32 + j] * d);
    mfma_tail(a0, a1, Wt, c.Hs, row0, r, q, N);
}

// agg block mapping: XCD-partition swizzle (graph = (blockIdx>>2)&1) when
// swz, else linear split.
__device__ __forceinline__ void agg_map(int bi, int nb0, int swz,
                                        const Ctx& c0, const Ctx& c1,
                                        Ctx& c, int& b) {
    if (swz) {
        int graph = (bi >> 2) & 1;
        b = ((bi >> 3) << 2) | (bi & 3);
        c = graph ? c1 : c0;
    } else {
        b = bi; c = c0;
        if (b >= nb0) { c = c1; b -= nb0; }
    }
}

// 2 nodes per wave; per half: 2 groups x 16 lanes, lane s covers fp8
// channels 4s..4s+3. csr holds src<<6; gather offset = su | (s*4).
// R21: maxd scalarized via readfirstlane -> all burst limits are SGPR
// (s_cmp/s_cbranch, no exec churn); two 8-deep bursts with scalar 2-slot
// early-outs: depad granularity 2, <=8 loads in flight (R19 VGPR shape).
// Invalid slots -> sentinel N<<6 (zeros).
__device__ __forceinline__ void agg_node2(const unsigned char* __restrict__ Hs,
                                          const unsigned int* __restrict__ csr,
                                          int beg, int deg, int maxd, int lane,
                                          unsigned int sent, float2v* acc) {
    int hbase = lane & 32;
    int hl = lane & 31;
    int g = (lane >> 4) & 1;
    unsigned int s4 = (unsigned int)((lane & 15) * 4);
    int maxs = __builtin_amdgcn_readfirstlane(maxd);   // wave-uniform -> SGPR
    for (int base = 0; base < maxs; base += 32) {
        unsigned int idx = (base + hl < deg) ? csr[beg + base + hl] : sent;
        int mW = maxs - base; if (mW > 32) mW = 32;     // scalar
        for (int t = 0; t < mW; t += 16) {              // scalar loop
            int lim = mW - t; if (lim > 16) lim = 16;   // scalar
            unsigned int h[8];
#pragma unroll
            for (int u = 0; u < 8; ++u) {               // issue phase
                if (2 * u >= lim) break;                // SGPR cmp -> s_cbranch
                unsigned int su = (unsigned int)__shfl((int)idx, hbase + t + 2 * u + g, 64);
                h[u] = *(const unsigned int*)(Hs + (su | s4));   // saddr + voffset
            }
#pragma unroll
            for (int u = 0; u < 8; ++u) {               // consume phase
                if (2 * u >= lim) break;
                acc[0] += up8lo(h[u]); acc[1] += up8hi(h[u]);    // sentinel adds 0
            }
        }
    }
    // merge the half's 2 groups (bit 4); does not cross halves
#pragma unroll
    for (int k = 0; k < 2; ++k) {
        float2v o;
        o.x = __shfl_xor(acc[k].x, 16, 64); o.y = __shfl_xor(acc[k].y, 16, 64);
        acc[k] += o;
    }
}

// layer-1 + fused GEMM2: v = dinv * relu(b + dinv * agg); rows staged in
// LDS as bf16 (XOR-swizzled at 16B granularity), one barrier, each wave
// MFMAs one 16-col tile of W2 (rows 8..15 zero) and stores fp8 Hs2.
// Hs2 sentinel row N zeroed here (aliases temp).
__global__ __launch_bounds__(256) void k_agg1(Ctx c0, Ctx c1, int nb0, int swz,
                                              const float* __restrict__ bias,
                                              const unsigned short* __restrict__ Wt2,
                                              int n) {
    __shared__ unsigned short As[8][64];
    Ctx c; int b;
    agg_map(blockIdx.x, nb0, swz, c0, c1, c, b);
    int wave = threadIdx.x >> 6, lane = threadIdx.x & 63;
    int h = lane >> 5;
    int node = b * 8 + wave * 2 + h;
    int nd = node < n ? node : 0;
    int beg = c.row_ptr[nd];
    int deg = (node < n) ? c.degA[nd] : 0;
    int od = __shfl_xor(deg, 32, 64);
    int maxd = deg > od ? deg : od;      // wave-uniform
    if (b == 0 && threadIdx.x < 64) c.Hs2[(size_t)n * 64 + threadIdx.x] = 0;
    float2v acc[2] = {{0.f, 0.f}, {0.f, 0.f}};
    agg_node2(c.Hs, c.csr, beg, deg, maxd, lane, (unsigned int)n << 6, acc);
    if (((lane >> 4) & 1) == 0) {
        int s = lane & 15;
        ushort4 o = {0, 0, 0, 0};
        if (node < n) {
            unsigned int hv = *(const unsigned int*)(c.Hs + (size_t)node * 64 + s * 4);
            float2v h0 = up8lo(hv), h1 = up8hi(hv);
            float4 bb = *(const float4*)(bias + s * 4);
            float d = c.dinv[node];
            o.x = f2bf(fmaxf(bb.x + d * (acc[0].x + h0.x), 0.0f) * d);
            o.y = f2bf(fmaxf(bb.y + d * (acc[0].y + h0.y), 0.0f) * d);
            o.z = f2bf(fmaxf(bb.z + d * (acc[1].x + h1.x), 0.0f) * d);
            o.w = f2bf(fmaxf(bb.w + d * (acc[1].y + h1.y), 0.0f) * d);
        }
        int row = wave * 2 + h;
        *(ushort4*)(&As[row][(s * 4) ^ ((row & 7) << 3)]) = o;   // swizzled
    }
    __syncthreads();
    // fused GEMM2: wave handles col-tile ct = wave; A rows 8..15 are zero.
    {
        int r = lane & 15, q = lane >> 4;
        short8 a0 = {}, a1 = {};
        if (r < 8) {
            int sw = (r & 7) << 3;
            a0 = *(const short8*)(&As[r][(q * 8) ^ sw]);
            a1 = *(const short8*)(&As[r][(q * 8 + 32) ^ sw]);
        }
        const unsigned short* wp = Wt2 + (wave * 16 + r) * 64 + q * 8;
        short8 b0 = *(const short8*)(wp);
        short8 b1 = *(const short8*)(wp + 32);
        f32x4 acc2 = {0.0f, 0.0f, 0.0f, 0.0f};
        acc2 = __builtin_amdgcn_mfma_f32_16x16x32_bf16(a0, b0, acc2, 0, 0, 0);
        acc2 = __builtin_amdgcn_mfma_f32_16x16x32_bf16(a1, b1, acc2, 0, 0, 0);
#pragma unroll
        for (int reg = 0; reg < 4; ++reg) {
            int l = q * 4 + reg;                     // local row 0..15
            int row = b * 8 + l;
            if (l < 8 && row < n)
                c.Hs2[(size_t)row * 64 + wave * 16 + r] = f2fp8(acc2[reg]);
        }
    }
}

// layer-2: block-reduce 8 relu'd rows -> P[block, f] (gathers from Hs2)
__global__ __launch_bounds__(256) void k_agg2(Ctx c0, Ctx c1, int nb0, int swz,
                                              const float* __restrict__ bias, int n) {
    __shared__ float red[8 * 64];
    Ctx c; int b;
    agg_map(blockIdx.x, nb0, swz, c0, c1, c, b);
    int wave = threadIdx.x >> 6, lane = threadIdx.x & 63;
    int h = lane >> 5;
    int node = b * 8 + wave * 2 + h;
    int nd = node < n ? node : 0;
    int beg = c.row_ptr[nd];
    int deg = (node < n) ? c.degA[nd] : 0;
    int od = __shfl_xor(deg, 32, 64);
    int maxd = deg > od ? deg : od;
    float2v acc[2] = {{0.f, 0.f}, {0.f, 0.f}};
    agg_node2(c.Hs2, c.csr, beg, deg, maxd, lane, (unsigned int)n << 6, acc);
    if (((lane >> 4) & 1) == 0) {
        int s = lane & 15;
        float4 v = {0.f, 0.f, 0.f, 0.f};
        if (node < n) {
            unsigned int hv = *(const unsigned int*)(c.Hs2 + (size_t)node * 64 + s * 4);
            float2v h0 = up8lo(hv), h1 = up8hi(hv);
            float4 bb = *(const float4*)(bias + s * 4);
            float d = c.dinv[node];
            v.x = fmaxf(bb.x + d * (acc[0].x + h0.x), 0.0f);
            v.y = fmaxf(bb.y + d * (acc[0].y + h0.y), 0.0f);
            v.z = fmaxf(bb.z + d * (acc[1].x + h1.x), 0.0f);
            v.w = fmaxf(bb.w + d * (acc[1].y + h1.y), 0.0f);
        }
        *(float4*)(&red[(wave * 2 + h) * 64 + s * 4]) = v;
    }
    __syncthreads();
    if (threadIdx.x < 64) {
        float acc8 = 0.0f;
#pragma unroll
        for (int r = 0; r < 8; ++r) acc8 += red[r * 64 + threadIdx.x];
        c.P[(size_t)b * 64 + threadIdx.x] = acc8;
    }
}

// colsum -> per-block partials in P2 (no atomics, no zero pass)
__global__ void k_colsum(Ctx c0, Ctx c1, int nb0, int rows) {
    int b = blockIdx.x; Ctx c = c0;
    if (b >= nb0) { c = c1; b -= nb0; }
    int f = threadIdx.x;  // 64
    float acc = 0.0f;
    for (int r = b; r < rows; r += nb0) acc += c.P[(size_t)r * 64 + f];
    c.P2[b * 64 + f] = acc;
}

// single-wave FC: reduce 256 partial rows, then out = fcb + (S/n) @ fcw^T
__global__ void k_fc(Ctx c0, Ctx c1, const float* __restrict__ fcw,
                     const float* __restrict__ fcb, int n) {
    Ctx c = blockIdx.x ? c1 : c0;
    __shared__ float S[64];
    int j = threadIdx.x;  // 64
    float s = 0.0f;
    for (int r = 0; r < 256; ++r) s += c.P2[r * 64 + j];
    S[j] = s;
    __syncthreads();
    float inv = 1.0f / (float)n;
    float acc = fcb[j];
#pragma unroll
    for (int k = 0; k < 64; ++k) acc += (S[k] * inv) * fcw[j * 64 + k];
    c.outp[j] = acc;
}

extern "C" void kernel_launch(void* const* d_in, const int* in_sizes, int n_in,
                              void* d_out, int out_size, void* d_ws, size_t ws_size,
                              hipStream_t stream) {
    const float* x[2]  = {(const float*)d_in[0], (const float*)d_in[1]};
    const int*   ei[2] = {(const int*)d_in[2], (const int*)d_in[3]};
    const float* W1  = (const float*)d_in[4];
    const float* b1  = (const float*)d_in[5];
    const float* W2  = (const float*)d_in[6];
    const float* b2  = (const float*)d_in[7];
    const float* fcw = (const float*)d_in[8];
    const float* fcb = (const float*)d_in[9];
    float* out = (float*)d_out;

    const int N  = in_sizes[0] / 64;
    const int E  = in_sizes[2] / 2;
    const int NF = N * 64;
    const int K  = (N + CHUNK - 1) / CHUNK;     // 782 buckets
    const int gGm = (N + 7) / 8;                // aggregate blocks (8 nodes each)
    const int nTiles = (N + 15) / 16;
    const int gMf = (nTiles + 3) / 4;
    const int gBin = (E + EPB - 1) / EPB;
    const int gK  = (K + TPB - 1) / TPB;

    auto al = [](size_t x) { return (x + 127) & ~(size_t)127; };
    size_t tempB = (size_t)K * CAP * 4;
    size_t hs2B  = (size_t)NF + 64;                    // fp8 + sentinel row N
    size_t szRegion = al(tempB > hs2B ? tempB : hs2B); // Hs2 aliases temp
    size_t szHs  = al((size_t)NF + 64);                // fp8 + sentinel row N
    size_t szCsr = al((size_t)K * CAP * 4);            // bucket-major, stride CAP
    size_t szRp  = al((size_t)N * 4);                  // beg only
    size_t szDeg = al((size_t)N * 4);
    size_t szDi  = al((size_t)N * 4);
    size_t szCu  = al((size_t)K * CPAD * 4);           // padded cursors
    size_t szP   = al((size_t)gGm * 64 * 4);
    size_t szP2  = al((size_t)256 * 64 * 4);
    size_t setB  = szRegion + szHs + szCsr + szRp + szDeg + szDi + szCu + szP + szP2;
    size_t wtB   = 2 * al(64 * 64 * 2);
    bool batched = ws_size >= wtB + 2 * setB;

    char* base = (char*)d_ws;
    unsigned short* Wt1 = (unsigned short*)base;
    unsigned short* Wt2 = (unsigned short*)(base + al(64 * 64 * 2));

    auto mkctx = [&](int g, char* p) {
        Ctx c;
        c.X = x[g]; c.esrc = ei[g]; c.edst = ei[g] + E;
        c.temp = (unsigned int*)p; c.Hs2 = (unsigned char*)p; p += szRegion;
        c.Hs = (unsigned char*)p; p += szHs;
        c.csr = (unsigned int*)p; p += szCsr;
        c.row_ptr = (int*)p; p += szRp;
        c.degA = (int*)p; p += szDeg;
        c.dinv = (float*)p; p += szDi;
        c.cursorG = (int*)p; p += szCu;
        c.P = (float*)p; p += szP;
        c.P2 = (float*)p;
        c.outp = out + g * 64;
        return c;
    };
    char* set0 = base + wtB;
    Ctx c0 = mkctx(0, set0);
    Ctx c1 = mkctx(1, batched ? set0 + setB : set0);   // fallback: shares set0

    k_prepW2<<<2, 256, 0, stream>>>(W1, W2, Wt1, Wt2);

    auto pipe = [&](Ctx A, Ctx B, int mult) {
        int swz = (mult == 2 && (gGm & 3) == 0) ? 1 : 0;
        k_zeroCur<<<mult * gK, TPB, 0, stream>>>(A, B, gK, K, N);
        k_binA<<<mult * gBin, 1024, 0, stream>>>(A, B, gBin, E, K);
        k_csrb<<<mult * K, 256, 0, stream>>>(A, B, K, N);
        k_gemm1<<<mult * gMf, 256, 0, stream>>>(A, B, gMf, Wt1, nTiles, N);
        k_agg1<<<mult * gGm, 256, 0, stream>>>(A, B, gGm, swz, b1, Wt2, N);
        k_agg2<<<mult * gGm, 256, 0, stream>>>(A, B, gGm, swz, b2, N);
        k_colsum<<<mult * 256, 64, 0, stream>>>(A, B, 256, gGm);
        k_fc<<<mult, 64, 0, stream>>>(A, B, fcw, fcb, N);
    };

    if (batched) {
        pipe(c0, c1, 2);
    } else {
        pipe(c0, c0, 1);   // sequential, shared buffer set
        pipe(c1, c1, 1);
    }
}

// Round 3
// 285.419 us; speedup vs baseline: 1.1147x; 1.0669x over previous
//
#include <hip/hip_runtime.h>

// SiameseGNN round 22: two node-pairs per wave, software-pipelined gathers.
//
// R21 evidence: k_agg1 stuck at 66.6us with VALU 52%, HBM 22%, MFMA 2%,
// conflicts 0 -- latency-bound. Chain per pair: cold csr idx load (~900cy,
// csr lines touched once) -> bpermute (~120cy) -> random 64B gather
// (~300-600cy) ~= 1400cy vs ~150cy VALU work -> need ~9 waves/SIMD to
// hide, have ~6.
//   fix: each wave handles TWO pairs (block = 16 nodes). Both idx loads
//        issue together (overlapping the 900cy long poles); gather windows
//        interleave: issueA0,issueA1,consA0,issueB0,consA1,issueB1,consB0,
//        consB1 -> ~16 loads in flight at every wait, independent work
//        behind each s_waitcnt. Guards stay scalar (readfirstlane maxd,
//        R21 shape). h regs 8x2 -> ~48 VGPR, under the 64/8-wave cliff.
//   bonus: fused GEMM2 A-tile now has 16 valid rows (no zero padding),
//        blocks halve; gGm padded to %4 so the XCD graph-split swizzle
//        stays on.
// Everything else unchanged from R21.

#define TPB    256
#define CHUNK  128
#define SHIFT  7
#define KMAX   1024
#define CAP    2560
#define EPB    8192
#define CPAD   16      // cursorG stride (ints)

typedef __attribute__((ext_vector_type(8))) short short8;
typedef __attribute__((ext_vector_type(4))) float f32x4;
typedef __attribute__((ext_vector_type(2))) float float2v;

struct Ctx {
    const float* X; const int* esrc; const int* edst;
    unsigned int* temp; unsigned char* Hs2; unsigned char* Hs;
    unsigned int* csr; int* row_ptr; int* degA; float* dinv; int* cursorG;
    float* P; float* P2; float* outp;
};

__device__ __forceinline__ unsigned short f2bf(float x) {
    union { float f; unsigned int i; } c; c.f = x;
    unsigned int r = c.i + 0x7FFFu + ((c.i >> 16) & 1u);   // RNE
    return (unsigned short)(r >> 16);
}
__device__ __forceinline__ unsigned char f2fp8(float x) {
    int p = __builtin_amdgcn_cvt_pk_fp8_f32(x, x, 0, false);
    return (unsigned char)(p & 0xFF);
}
__device__ __forceinline__ float2v up8lo(unsigned int w) {
    return __builtin_amdgcn_cvt_pk_f32_fp8(w, false);
}
__device__ __forceinline__ float2v up8hi(unsigned int w) {
    return __builtin_amdgcn_cvt_pk_f32_fp8(w, true);
}

__global__ void k_prepW2(const float* __restrict__ W1, const float* __restrict__ W2,
                         unsigned short* __restrict__ Wt1, unsigned short* __restrict__ Wt2) {
    const float* W = blockIdx.x ? W2 : W1;
    unsigned short* Wt = blockIdx.x ? Wt2 : Wt1;
    for (int i = threadIdx.x; i < 64 * 64; i += 256) {
        int n = i >> 6, k = i & 63;
        Wt[i] = f2bf(W[k * 64 + n]);
    }
}

// zero cursors + zero the Hs sentinel row (row N; ws re-poisoned per call)
__global__ void k_zeroCur(Ctx c0, Ctx c1, int nb0, int K, int N) {
    int b = blockIdx.x; Ctx c = c0;
    if (b >= nb0) { c = c1; b -= nb0; }
    int i = b * blockDim.x + threadIdx.x;
    if (i < K) c.cursorG[i * CPAD] = 0;
    if (b == 0 && threadIdx.x < 64) c.Hs[(size_t)N * 64 + threadIdx.x] = 0;
}

// binA: LDS counting sort per block, burst segment writes. 1024 threads.
__global__ __launch_bounds__(1024) void k_binA(Ctx c0, Ctx c1, int nb0, int E, int K) {
    __shared__ int cnt[KMAX];
    __shared__ int ofs[KMAX];
    __shared__ int segBase[KMAX];
    __shared__ unsigned int sorted[EPB];
    __shared__ unsigned short bkt[EPB];
    int b = blockIdx.x; Ctx c = c0;
    if (b >= nb0) { c = c1; b -= nb0; }
    int tid = threadIdx.x;               // 0..1023 == KMAX
    cnt[tid] = 0;
    __syncthreads();
    int base = b * EPB;
    int tot = E - base; if (tot > EPB) tot = EPB;
#pragma unroll
    for (int k = 0; k < EPB / 1024; ++k) {
        int e = base + k * 1024 + tid;
        if (e < E) atomicAdd(&cnt[c.edst[e] >> SHIFT], 1);
    }
    __syncthreads();
    int v = cnt[tid];
    segBase[tid] = v;
    __syncthreads();
#pragma unroll
    for (int off = 1; off < 1024; off <<= 1) {
        int t = (tid >= off) ? segBase[tid - off] : 0;
        __syncthreads();
        segBase[tid] += t;
        __syncthreads();
    }
    ofs[tid] = segBase[tid] - v;
    __syncthreads();
    if (tid < K) {
        segBase[tid] = v ? atomicAdd(&c.cursorG[tid * CPAD], v) : 0;
    } else {
        segBase[tid] = 0;
    }
    cnt[tid] = 0;
    __syncthreads();
#pragma unroll
    for (int k = 0; k < EPB / 1024; ++k) {
        int e = base + k * 1024 + tid;
        if (e < E) {
            int d = c.edst[e];
            int bk = d >> SHIFT;
            int r = atomicAdd(&cnt[bk], 1);
            int p = ofs[bk] + r;
            sorted[p] = ((unsigned int)(d & (CHUNK - 1)) << 17) | (unsigned int)c.esrc[e];
            bkt[p] = (unsigned short)bk;
        }
    }
    __syncthreads();
    for (int p = tid; p < tot; p += 1024) {
        unsigned int vv = sorted[p];
        int bk = bkt[p];
        int pos = segBase[bk] + (p - ofs[bk]);
        if (pos < CAP) c.temp[(size_t)bk * CAP + pos] = vv;
    }
}

// Per-bucket LDS counting sort -> bucket-major csr slice (stride CAP) +
// row_ptr (beg) + deg + dinv. csr stores src<<6 (pre-shifted byte offset).
__global__ __launch_bounds__(256) void k_csrb(Ctx c0, Ctx c1, int nb0, int N) {
    __shared__ int deg[CHUNK];
    __shared__ int lofs[CHUNK];
    __shared__ int cur[CHUNK];
    int b = blockIdx.x; Ctx c = c0;
    if (b >= nb0) { c = c1; b -= nb0; }
    int tid = threadIdx.x;
    if (tid < CHUNK) deg[tid] = 0;
    __syncthreads();
    int cnt = c.cursorG[b * CPAD]; if (cnt > CAP) cnt = CAP;
    const size_t tb = (size_t)b * CAP;
    for (int i = tid; i < cnt; i += 256) atomicAdd(&deg[c.temp[tb + i] >> 17], 1);
    __syncthreads();
    if (tid < CHUNK) lofs[tid] = deg[tid];
    __syncthreads();
#pragma unroll
    for (int off = 1; off < CHUNK; off <<= 1) {
        int t = (tid < CHUNK && tid >= off) ? lofs[tid - off] : 0;
        __syncthreads();
        if (tid < CHUNK) lofs[tid] += t;
        __syncthreads();
    }
    int base = b * CAP;                  // bucket-major: no global scan needed
    if (tid < CHUNK) {
        int excl = lofs[tid] - deg[tid];
        lofs[tid] = excl;
        cur[tid] = 0;
        int node = b * CHUNK + tid;
        if (node < N) {
            c.row_ptr[node] = base + excl;
            c.degA[node] = deg[tid];
            c.dinv[node] = rsqrtf((float)deg[tid] + 1.0f);
        }
    }
    __syncthreads();
    for (int i = tid; i < cnt; i += 256) {
        unsigned int p = c.temp[tb + i];
        int dl = p >> 17;
        int rank = atomicAdd(&cur[dl], 1);
        c.csr[base + lofs[dl] + rank] = (p & 0x1FFFFu) << 6;   // src byte offset
    }
}

// Shared MFMA body: A-fragments provided; B from Wt; store fp8 Hs.
__device__ __forceinline__ void mfma_tail(short8 a0, short8 a1,
                                          const unsigned short* __restrict__ Wt,
                                          unsigned char* __restrict__ Hs,
                                          int row0, int r, int q, int N) {
    short8 bfrag[4][2];
#pragma unroll
    for (int ct = 0; ct < 4; ++ct)
#pragma unroll
        for (int kb = 0; kb < 2; ++kb)
            bfrag[ct][kb] = *(const short8*)(Wt + (ct * 16 + r) * 64 + q * 8 + 32 * kb);
    f32x4 acc[4];
#pragma unroll
    for (int ct = 0; ct < 4; ++ct) {
        acc[ct] = (f32x4){0.0f, 0.0f, 0.0f, 0.0f};
        acc[ct] = __builtin_amdgcn_mfma_f32_16x16x32_bf16(a0, bfrag[ct][0], acc[ct], 0, 0, 0);
        acc[ct] = __builtin_amdgcn_mfma_f32_16x16x32_bf16(a1, bfrag[ct][1], acc[ct], 0, 0, 0);
    }
#pragma unroll
    for (int reg = 0; reg < 4; ++reg) {
        int row = row0 + q * 4 + reg;
        if (row < N) {
            size_t base = (size_t)row * 64 + r;
#pragma unroll
            for (int ct = 0; ct < 4; ++ct)
                Hs[base + ct * 16] = f2fp8(acc[ct][reg]);
        }
    }
}

// GEMM1: fp32 X in, dinv folded into A-fragment conversion.
__global__ __launch_bounds__(256) void k_gemm1(Ctx c0, Ctx c1, int nb0,
                                               const unsigned short* __restrict__ Wt,
                                               int nTiles, int N) {
    int b = blockIdx.x; Ctx c = c0;
    if (b >= nb0) { c = c1; b -= nb0; }
    int wave = threadIdx.x >> 6, lane = threadIdx.x & 63;
    int tile = b * 4 + wave;
    if (tile >= nTiles) return;
    int r = lane & 15, q = lane >> 4;
    int row0 = tile * 16;
    int row = row0 + r;
    int rr = row < N ? row : N - 1;
    float d = c.dinv[rr];
    const float* xrow = c.X + (size_t)rr * 64 + q * 8;
    short8 a0, a1;
#pragma unroll
    for (int j = 0; j < 8; ++j) a0[j] = (short)f2bf(xrow[j] * d);
#pragma unroll
    for (int j = 0; j < 8; ++j) a1[j] = (short)f2bf(xrow[32 + j] * d);
    mfma_tail(a0, a1, Wt, c.Hs, row0, r, q, N);
}

// agg block mapping: XCD-partition swizzle (graph = (blockIdx>>2)&1) when
// swz, else linear split.
__device__ __forceinline__ void agg_map(int bi, int nb0, int swz,
                                        const Ctx& c0, const Ctx& c1,
                                        Ctx& c, int& b) {
    if (swz) {
        int graph = (bi >> 2) & 1;
        b = ((bi >> 3) << 2) | (bi & 3);
        c = graph ? c1 : c0;
    } else {
        b = bi; c = c0;
        if (b >= nb0) { c = c1; b -= nb0; }
    }
}

// 8-slot issue/consume windows; slotbase compile-time, lim scalar (SGPR).
__device__ __forceinline__ void agg_issue8(const unsigned char* __restrict__ Hs,
                                           unsigned int idx, int slotbase, int lim,
                                           int hbase, int g, unsigned int s4,
                                           unsigned int* h) {
#pragma unroll
    for (int u = 0; u < 8; ++u) {
        if (slotbase + 2 * u >= lim) break;   // SGPR cmp -> s_cbranch
        unsigned int su = (unsigned int)__shfl((int)idx, hbase + slotbase + 2 * u + g, 64);
        h[u] = *(const unsigned int*)(Hs + (su | s4));
    }
}
__device__ __forceinline__ void agg_cons8(const unsigned int* h, int slotbase, int lim,
                                          float2v* acc) {
#pragma unroll
    for (int u = 0; u < 8; ++u) {
        if (slotbase + 2 * u >= lim) break;
        acc[0] += up8lo(h[u]); acc[1] += up8hi(h[u]);   // sentinel adds 0
    }
}

// Two node-pairs per wave, pipelined: both cold idx loads overlap, then
// interleaved issue/consume windows keep ~16 gathers in flight at every
// wait point. Per half: 2 groups x 16 lanes, lane s covers fp8 channels
// 4s..4s+3. csr holds src<<6; gather offset = su | (s*4). Invalid slots
// -> sentinel N<<6 (zeros).
__device__ __forceinline__ void agg_pair2(const unsigned char* __restrict__ Hs,
                                          const unsigned int* __restrict__ csr,
                                          int beg0, int deg0, int maxs0,
                                          int beg1, int deg1, int maxs1,
                                          int lane, unsigned int sent,
                                          float2v* acc0, float2v* acc1) {
    int hbase = lane & 32;
    int hl = lane & 31;
    int g = (lane >> 4) & 1;
    unsigned int s4 = (unsigned int)((lane & 15) * 4);
    unsigned int idx0 = (hl < deg0) ? csr[beg0 + hl] : sent;
    unsigned int idx1 = (hl < deg1) ? csr[beg1 + hl] : sent;
    int lim0 = maxs0 > 32 ? 32 : maxs0;   // scalar
    int lim1 = maxs1 > 32 ? 32 : maxs1;   // scalar
    unsigned int h0[8], h1[8];
    agg_issue8(Hs, idx0, 0, lim0, hbase, g, s4, h0);
    agg_issue8(Hs, idx1, 0, lim1, hbase, g, s4, h1);
    agg_cons8(h0, 0, lim0, acc0);
    if (lim0 > 16) agg_issue8(Hs, idx0, 16, lim0, hbase, g, s4, h0);
    agg_cons8(h1, 0, lim1, acc1);
    if (lim1 > 16) agg_issue8(Hs, idx1, 16, lim1, hbase, g, s4, h1);
    if (lim0 > 16) agg_cons8(h0, 16, lim0, acc0);
    if (lim1 > 16) agg_cons8(h1, 16, lim1, acc1);
    // rare deep tails (deg > 32)
    for (int base = 32; base < maxs0; base += 32) {
        unsigned int idx = (base + hl < deg0) ? csr[beg0 + base + hl] : sent;
        int lim = maxs0 - base; if (lim > 32) lim = 32;
        unsigned int hh[8];
        agg_issue8(Hs, idx, 0, lim, hbase, g, s4, hh);
        agg_cons8(hh, 0, lim, acc0);
        if (lim > 16) {
            agg_issue8(Hs, idx, 16, lim, hbase, g, s4, hh);
            agg_cons8(hh, 16, lim, acc0);
        }
    }
    for (int base = 32; base < maxs1; base += 32) {
        unsigned int idx = (base + hl < deg1) ? csr[beg1 + base + hl] : sent;
        int lim = maxs1 - base; if (lim > 32) lim = 32;
        unsigned int hh[8];
        agg_issue8(Hs, idx, 0, lim, hbase, g, s4, hh);
        agg_cons8(hh, 0, lim, acc1);
        if (lim > 16) {
            agg_issue8(Hs, idx, 16, lim, hbase, g, s4, hh);
            agg_cons8(hh, 16, lim, acc1);
        }
    }
    // merge the half's 2 groups (bit 4); does not cross halves
#pragma unroll
    for (int k = 0; k < 2; ++k) {
        float2v o;
        o.x = __shfl_xor(acc0[k].x, 16, 64); o.y = __shfl_xor(acc0[k].y, 16, 64);
        acc0[k] += o;
        o.x = __shfl_xor(acc1[k].x, 16, 64); o.y = __shfl_xor(acc1[k].y, 16, 64);
        acc1[k] += o;
    }
}

// layer-1 + fused GEMM2: block = 16 nodes (4 waves x 2 pairs). v = dinv *
// relu(b + dinv * agg); rows staged in LDS bf16 (XOR-swizzled), one
// barrier, each wave MFMAs one 16-col tile of W2 (all 16 rows valid now),
// stores fp8 Hs2. Hs2 sentinel row N zeroed here (aliases temp).
__global__ __launch_bounds__(256) void k_agg1(Ctx c0, Ctx c1, int nb0, int swz,
                                              const float* __restrict__ bias,
                                              const unsigned short* __restrict__ Wt2,
                                              int n) {
    __shared__ unsigned short As[16][64];
    Ctx c; int b;
    agg_map(blockIdx.x, nb0, swz, c0, c1, c, b);
    int wave = threadIdx.x >> 6, lane = threadIdx.x & 63;
    int h = lane >> 5;
    int nbase = b * 16 + wave * 4;
    int node0 = nbase + h;
    int node1 = nbase + 2 + h;
    int nd0 = node0 < n ? node0 : 0;
    int nd1 = node1 < n ? node1 : 0;
    int beg0 = c.row_ptr[nd0];
    int beg1 = c.row_ptr[nd1];
    int deg0 = (node0 < n) ? c.degA[nd0] : 0;
    int deg1 = (node1 < n) ? c.degA[nd1] : 0;
    int od0 = __shfl_xor(deg0, 32, 64); int m0 = deg0 > od0 ? deg0 : od0;
    int od1 = __shfl_xor(deg1, 32, 64); int m1 = deg1 > od1 ? deg1 : od1;
    int maxs0 = __builtin_amdgcn_readfirstlane(m0);
    int maxs1 = __builtin_amdgcn_readfirstlane(m1);
    if (b == 0 && threadIdx.x < 64) c.Hs2[(size_t)n * 64 + threadIdx.x] = 0;
    float2v acc0[2] = {{0.f, 0.f}, {0.f, 0.f}};
    float2v acc1[2] = {{0.f, 0.f}, {0.f, 0.f}};
    agg_pair2(c.Hs, c.csr, beg0, deg0, maxs0, beg1, deg1, maxs1,
              lane, (unsigned int)n << 6, acc0, acc1);
    if (((lane >> 4) & 1) == 0) {
        int s = lane & 15;
#pragma unroll
        for (int pr = 0; pr < 2; ++pr) {
            const float2v* ac = pr ? acc1 : acc0;
            int node = nbase + pr * 2 + h;
            ushort4 o = {0, 0, 0, 0};
            if (node < n) {
                unsigned int hv = *(const unsigned int*)(c.Hs + (size_t)node * 64 + s * 4);
                float2v h0 = up8lo(hv), h1 = up8hi(hv);
                float4 bb = *(const float4*)(bias + s * 4);
                float d = c.dinv[node];
                o.x = f2bf(fmaxf(bb.x + d * (ac[0].x + h0.x), 0.0f) * d);
                o.y = f2bf(fmaxf(bb.y + d * (ac[0].y + h0.y), 0.0f) * d);
                o.z = f2bf(fmaxf(bb.z + d * (ac[1].x + h1.x), 0.0f) * d);
                o.w = f2bf(fmaxf(bb.w + d * (ac[1].y + h1.y), 0.0f) * d);
            }
            int row = wave * 4 + pr * 2 + h;
            *(ushort4*)(&As[row][(s * 4) ^ ((row & 7) << 3)]) = o;   // swizzled
        }
    }
    __syncthreads();
    // fused GEMM2: wave handles col-tile ct = wave; all 16 A rows valid.
    {
        int r = lane & 15, q = lane >> 4;
        int sw = (r & 7) << 3;
        short8 a0 = *(const short8*)(&As[r][(q * 8) ^ sw]);
        short8 a1 = *(const short8*)(&As[r][(q * 8 + 32) ^ sw]);
        const unsigned short* wp = Wt2 + (wave * 16 + r) * 64 + q * 8;
        short8 b0 = *(const short8*)(wp);
        short8 b1 = *(const short8*)(wp + 32);
        f32x4 acc2 = {0.0f, 0.0f, 0.0f, 0.0f};
        acc2 = __builtin_amdgcn_mfma_f32_16x16x32_bf16(a0, b0, acc2, 0, 0, 0);
        acc2 = __builtin_amdgcn_mfma_f32_16x16x32_bf16(a1, b1, acc2, 0, 0, 0);
#pragma unroll
        for (int reg = 0; reg < 4; ++reg) {
            int l = q * 4 + reg;                     // local row 0..15
            int row = b * 16 + l;
            if (row < n)
                c.Hs2[(size_t)row * 64 + wave * 16 + r] = f2fp8(acc2[reg]);
        }
    }
}

// layer-2: block = 16 nodes; block-reduce 16 relu'd rows -> P[block, f]
// (gathers from Hs2)
__global__ __launch_bounds__(256) void k_agg2(Ctx c0, Ctx c1, int nb0, int swz,
                                              const float* __restrict__ bias, int n) {
    __shared__ float red[16 * 64];
    Ctx c; int b;
    agg_map(blockIdx.x, nb0, swz, c0, c1, c, b);
    int wave = threadIdx.x >> 6, lane = threadIdx.x & 63;
    int h = lane >> 5;
    int nbase = b * 16 + wave * 4;
    int node0 = nbase + h;
    int node1 = nbase + 2 + h;
    int nd0 = node0 < n ? node0 : 0;
    int nd1 = node1 < n ? node1 : 0;
    int beg0 = c.row_ptr[nd0];
    int beg1 = c.row_ptr[nd1];
    int deg0 = (node0 < n) ? c.degA[nd0] : 0;
    int deg1 = (node1 < n) ? c.degA[nd1] : 0;
    int od0 = __shfl_xor(deg0, 32, 64); int m0 = deg0 > od0 ? deg0 : od0;
    int od1 = __shfl_xor(deg1, 32, 64); int m1 = deg1 > od1 ? deg1 : od1;
    int maxs0 = __builtin_amdgcn_readfirstlane(m0);
    int maxs1 = __builtin_amdgcn_readfirstlane(m1);
    float2v acc0[2] = {{0.f, 0.f}, {0.f, 0.f}};
    float2v acc1[2] = {{0.f, 0.f}, {0.f, 0.f}};
    agg_pair2(c.Hs2, c.csr, beg0, deg0, maxs0, beg1, deg1, maxs1,
              lane, (unsigned int)n << 6, acc0, acc1);
    if (((lane >> 4) & 1) == 0) {
        int s = lane & 15;
#pragma unroll
        for (int pr = 0; pr < 2; ++pr) {
            const float2v* ac = pr ? acc1 : acc0;
            int node = nbase + pr * 2 + h;
            float4 v = {0.f, 0.f, 0.f, 0.f};
            if (node < n) {
                unsigned int hv = *(const unsigned int*)(c.Hs2 + (size_t)node * 64 + s * 4);
                float2v h0 = up8lo(hv), h1 = up8hi(hv);
                float4 bb = *(const float4*)(bias + s * 4);
                float d = c.dinv[node];
                v.x = fmaxf(bb.x + d * (ac[0].x + h0.x), 0.0f);
                v.y = fmaxf(bb.y + d * (ac[0].y + h0.y), 0.0f);
                v.z = fmaxf(bb.z + d * (ac[1].x + h1.x), 0.0f);
                v.w = fmaxf(bb.w + d * (ac[1].y + h1.y), 0.0f);
            }
            *(float4*)(&red[(wave * 4 + pr * 2 + h) * 64 + s * 4]) = v;
        }
    }
    __syncthreads();
    if (threadIdx.x < 64) {
        float acc16 = 0.0f;
#pragma unroll
        for (int r = 0; r < 16; ++r) acc16 += red[r * 64 + threadIdx.x];
        c.P[(size_t)b * 64 + threadIdx.x] = acc16;
    }
}

// colsum -> per-block partials in P2 (no atomics, no zero pass)
__global__ void k_colsum(Ctx c0, Ctx c1, int nb0, int rows) {
    int b = blockIdx.x; Ctx c = c0;
    if (b >= nb0) { c = c1; b -= nb0; }
    int f = threadIdx.x;  // 64
    float acc = 0.0f;
    for (int r = b; r < rows; r += nb0) acc += c.P[(size_t)r * 64 + f];
    c.P2[b * 64 + f] = acc;
}

// single-wave FC: reduce 256 partial rows, then out = fcb + (S/n) @ fcw^T
__global__ void k_fc(Ctx c0, Ctx c1, const float* __restrict__ fcw,
                     const float* __restrict__ fcb, int n) {
    Ctx c = blockIdx.x ? c1 : c0;
    __shared__ float S[64];
    int j = threadIdx.x;  // 64
    float s = 0.0f;
    for (int r = 0; r < 256; ++r) s += c.P2[r * 64 + j];
    S[j] = s;
    __syncthreads();
    float inv = 1.0f / (float)n;
    float acc = fcb[j];
#pragma unroll
    for (int k = 0; k < 64; ++k) acc += (S[k] * inv) * fcw[j * 64 + k];
    c.outp[j] = acc;
}

extern "C" void kernel_launch(void* const* d_in, const int* in_sizes, int n_in,
                              void* d_out, int out_size, void* d_ws, size_t ws_size,
                              hipStream_t stream) {
    const float* x[2]  = {(const float*)d_in[0], (const float*)d_in[1]};
    const int*   ei[2] = {(const int*)d_in[2], (const int*)d_in[3]};
    const float* W1  = (const float*)d_in[4];
    const float* b1  = (const float*)d_in[5];
    const float* W2  = (const float*)d_in[6];
    const float* b2  = (const float*)d_in[7];
    const float* fcw = (const float*)d_in[8];
    const float* fcb = (const float*)d_in[9];
    float* out = (float*)d_out;

    const int N  = in_sizes[0] / 64;
    const int E  = in_sizes[2] / 2;
    const int NF = N * 64;
    const int K  = (N + CHUNK - 1) / CHUNK;     // 782 buckets
    const int gGm  = (N + 15) / 16;             // aggregate blocks (16 nodes each)
    const int gGmP = (gGm + 3) & ~3;            // padded so swizzle stays legal
    const int nTiles = (N + 15) / 16;
    const int gMf = (nTiles + 3) / 4;
    const int gBin = (E + EPB - 1) / EPB;
    const int gK  = (K + TPB - 1) / TPB;

    auto al = [](size_t x) { return (x + 127) & ~(size_t)127; };
    size_t tempB = (size_t)K * CAP * 4;
    size_t hs2B  = (size_t)NF + 64;                    // fp8 + sentinel row N
    size_t szRegion = al(tempB > hs2B ? tempB : hs2B); // Hs2 aliases temp
    size_t szHs  = al((size_t)NF + 64);                // fp8 + sentinel row N
    size_t szCsr = al((size_t)K * CAP * 4);            // bucket-major, stride CAP
    size_t szRp  = al((size_t)N * 4);                  // beg only
    size_t szDeg = al((size_t)N * 4);
    size_t szDi  = al((size_t)N * 4);
    size_t szCu  = al((size_t)K * CPAD * 4);           // padded cursors
    size_t szP   = al((size_t)gGmP * 64 * 4);
    size_t szP2  = al((size_t)256 * 64 * 4);
    size_t setB  = szRegion + szHs + szCsr + szRp + szDeg + szDi + szCu + szP + szP2;
    size_t wtB   = 2 * al(64 * 64 * 2);
    bool batched = ws_size >= wtB + 2 * setB;

    char* base = (char*)d_ws;
    unsigned short* Wt1 = (unsigned short*)base;
    unsigned short* Wt2 = (unsigned short*)(base + al(64 * 64 * 2));

    auto mkctx = [&](int g, char* p) {
        Ctx c;
        c.X = x[g]; c.esrc = ei[g]; c.edst = ei[g] + E;
        c.temp = (unsigned int*)p; c.Hs2 = (unsigned char*)p; p += szRegion;
        c.Hs = (unsigned char*)p; p += szHs;
        c.csr = (unsigned int*)p; p += szCsr;
        c.row_ptr = (int*)p; p += szRp;
        c.degA = (int*)p; p += szDeg;
        c.dinv = (float*)p; p += szDi;
        c.cursorG = (int*)p; p += szCu;
        c.P = (float*)p; p += szP;
        c.P2 = (float*)p;
        c.outp = out + g * 64;
        return c;
    };
    char* set0 = base + wtB;
    Ctx c0 = mkctx(0, set0);
    Ctx c1 = mkctx(1, batched ? set0 + setB : set0);   // fallback: shares set0

    k_prepW2<<<2, 256, 0, stream>>>(W1, W2, Wt1, Wt2);

    auto pipe = [&](Ctx A, Ctx B, int mult) {
        int swz = (mult == 2) ? 1 : 0;   // gGmP is always %4 == 0
        k_zeroCur<<<mult * gK, TPB, 0, stream>>>(A, B, gK, K, N);
        k_binA<<<mult * gBin, 1024, 0, stream>>>(A, B, gBin, E, K);
        k_csrb<<<mult * K, 256, 0, stream>>>(A, B, K, N);
        k_gemm1<<<mult * gMf, 256, 0, stream>>>(A, B, gMf, Wt1, nTiles, N);
        k_agg1<<<mult * gGmP, 256, 0, stream>>>(A, B, gGmP, swz, b1, Wt2, N);
        k_agg2<<<mult * gGmP, 256, 0, stream>>>(A, B, gGmP, swz, b2, N);
        k_colsum<<<mult * 256, 64, 0, stream>>>(A, B, 256, gGmP);
        k_fc<<<mult, 64, 0, stream>>>(A, B, fcw, fcb, N);
    };

    if (batched) {
        pipe(c0, c1, 2);
    } else {
        pipe(c0, c0, 1);   // sequential, shared buffer set
        pipe(c1, c1, 1);
    }
}

// Round 4
// 280.683 us; speedup vs baseline: 1.1335x; 1.0169x over previous
//
#include <hip/hip_runtime.h>

// SiameseGNN round 23: dwordx2 gathers (32 edges in flight) + wave-scan
// in binA/csrb.
//
// R22 evidence: agg1 50.6us, VALU 47%, HBM 28%, MFMA 1%, occ 70% --
// still latency-bound; ~16 edges in flight per wave vs ~400cy gather
// latency is the binder.
//   fix 1: gather loads dword -> dwordx2 with 8-lane subgroups (8 lanes
//          x 8B cover a 64B row; one wave-instruction = 4 rows = 512B).
//          8-deep window now spans 32 slots: same 16 loads outstanding,
//          2x edges in flight, VMEM + shfl per edge halved. Epilogue
//          reshaped to 8 lanes x 8 channels (swizzle preserved at
//          8-element granularity -> MFMA read side untouched).
//          __launch_bounds__(256,8) pins <=64 VGPR (8 waves/SIMD).
//   fix 2: binA 1024-wide Hillis-Steele (20 barriers of a 16-wave block)
//          -> per-wave shfl_up scan + cross-wave fixup (2 barriers);
//          csrb 128-wide scan 15 -> 3 barriers.
// Everything else unchanged from R22 (2 pairs/wave, scalar guards,
// fused GEMM2, pre-shifted CSR, sentinel row, fp8, bucket-major csr,
// batching, XCD swizzle).

#define TPB    256
#define CHUNK  128
#define SHIFT  7
#define KMAX   1024
#define CAP    2560
#define EPB    8192
#define CPAD   16      // cursorG stride (ints)

typedef __attribute__((ext_vector_type(8))) short short8;
typedef __attribute__((ext_vector_type(4))) float f32x4;
typedef __attribute__((ext_vector_type(2))) float float2v;
typedef __attribute__((ext_vector_type(2))) unsigned int uint2v;

struct Ctx {
    const float* X; const int* esrc; const int* edst;
    unsigned int* temp; unsigned char* Hs2; unsigned char* Hs;
    unsigned int* csr; int* row_ptr; int* degA; float* dinv; int* cursorG;
    float* P; float* P2; float* outp;
};

__device__ __forceinline__ unsigned short f2bf(float x) {
    union { float f; unsigned int i; } c; c.f = x;
    unsigned int r = c.i + 0x7FFFu + ((c.i >> 16) & 1u);   // RNE
    return (unsigned short)(r >> 16);
}
__device__ __forceinline__ unsigned char f2fp8(float x) {
    int p = __builtin_amdgcn_cvt_pk_fp8_f32(x, x, 0, false);
    return (unsigned char)(p & 0xFF);
}
__device__ __forceinline__ float2v up8lo(unsigned int w) {
    return __builtin_amdgcn_cvt_pk_f32_fp8(w, false);
}
__device__ __forceinline__ float2v up8hi(unsigned int w) {
    return __builtin_amdgcn_cvt_pk_f32_fp8(w, true);
}

__global__ void k_prepW2(const float* __restrict__ W1, const float* __restrict__ W2,
                         unsigned short* __restrict__ Wt1, unsigned short* __restrict__ Wt2) {
    const float* W = blockIdx.x ? W2 : W1;
    unsigned short* Wt = blockIdx.x ? Wt2 : Wt1;
    for (int i = threadIdx.x; i < 64 * 64; i += 256) {
        int n = i >> 6, k = i & 63;
        Wt[i] = f2bf(W[k * 64 + n]);
    }
}

// zero cursors + zero the Hs sentinel row (row N; ws re-poisoned per call)
__global__ void k_zeroCur(Ctx c0, Ctx c1, int nb0, int K, int N) {
    int b = blockIdx.x; Ctx c = c0;
    if (b >= nb0) { c = c1; b -= nb0; }
    int i = b * blockDim.x + threadIdx.x;
    if (i < K) c.cursorG[i * CPAD] = 0;
    if (b == 0 && threadIdx.x < 64) c.Hs[(size_t)N * 64 + threadIdx.x] = 0;
}

// binA: LDS counting sort per block, burst segment writes. 1024 threads.
// R23: scan = per-wave shfl_up + cross-wave fixup (2 barriers, was 20).
__global__ __launch_bounds__(1024) void k_binA(Ctx c0, Ctx c1, int nb0, int E, int K) {
    __shared__ int cnt[KMAX];
    __shared__ int ofs[KMAX];
    __shared__ int segBase[KMAX];
    __shared__ int wsum[16];
    __shared__ unsigned int sorted[EPB];
    __shared__ unsigned short bkt[EPB];
    int b = blockIdx.x; Ctx c = c0;
    if (b >= nb0) { c = c1; b -= nb0; }
    int tid = threadIdx.x;               // 0..1023 == KMAX
    cnt[tid] = 0;
    __syncthreads();
    int base = b * EPB;
    int tot = E - base; if (tot > EPB) tot = EPB;
#pragma unroll
    for (int k = 0; k < EPB / 1024; ++k) {
        int e = base + k * 1024 + tid;
        if (e < E) atomicAdd(&cnt[c.edst[e] >> SHIFT], 1);
    }
    __syncthreads();
    int v = cnt[tid];
    int lane = tid & 63, w = tid >> 6;
    int x = v;                            // wave-inclusive scan
#pragma unroll
    for (int off = 1; off < 64; off <<= 1) {
        int t = __shfl_up(x, off, 64);
        if (lane >= off) x += t;
    }
    if (lane == 63) wsum[w] = x;
    __syncthreads();
    if (tid < 16) {
        int y = wsum[tid];
#pragma unroll
        for (int off = 1; off < 16; off <<= 1) {
            int t = __shfl_up(y, off, 16);
            if ((tid & 15) >= off) y += t;
        }
        wsum[tid] = y;                    // inclusive wave totals
    }
    __syncthreads();
    int pre = w ? wsum[w - 1] : 0;
    ofs[tid] = x + pre - v;               // exclusive scan
    if (tid < K) {
        segBase[tid] = v ? atomicAdd(&c.cursorG[tid * CPAD], v) : 0;
    } else {
        segBase[tid] = 0;
    }
    cnt[tid] = 0;
    __syncthreads();
#pragma unroll
    for (int k = 0; k < EPB / 1024; ++k) {
        int e = base + k * 1024 + tid;
        if (e < E) {
            int d = c.edst[e];
            int bk = d >> SHIFT;
            int r = atomicAdd(&cnt[bk], 1);
            int p = ofs[bk] + r;
            sorted[p] = ((unsigned int)(d & (CHUNK - 1)) << 17) | (unsigned int)c.esrc[e];
            bkt[p] = (unsigned short)bk;
        }
    }
    __syncthreads();
    for (int p = tid; p < tot; p += 1024) {
        unsigned int vv = sorted[p];
        int bk = bkt[p];
        int pos = segBase[bk] + (p - ofs[bk]);
        if (pos < CAP) c.temp[(size_t)bk * CAP + pos] = vv;
    }
}

// Per-bucket LDS counting sort -> bucket-major csr slice (stride CAP) +
// row_ptr (beg) + deg + dinv. csr stores src<<6 (pre-shifted byte offset).
// R23: 128-wide scan via wave shfl_up + fixup (3 barriers, was 15).
__global__ __launch_bounds__(256) void k_csrb(Ctx c0, Ctx c1, int nb0, int N) {
    __shared__ int deg[CHUNK];
    __shared__ int lofs[CHUNK];
    __shared__ int cur[CHUNK];
    __shared__ int wsum2[2];
    int b = blockIdx.x; Ctx c = c0;
    if (b >= nb0) { c = c1; b -= nb0; }
    int tid = threadIdx.x;
    if (tid < CHUNK) deg[tid] = 0;
    __syncthreads();
    int cnt = c.cursorG[b * CPAD]; if (cnt > CAP) cnt = CAP;
    const size_t tb = (size_t)b * CAP;
    for (int i = tid; i < cnt; i += 256) atomicAdd(&deg[c.temp[tb + i] >> 17], 1);
    __syncthreads();
    int vdeg = 0, x = 0;
    if (tid < CHUNK) { vdeg = deg[tid]; x = vdeg; }
#pragma unroll
    for (int off = 1; off < 64; off <<= 1) {
        int t = __shfl_up(x, off, 64);
        if ((tid & 63) >= off) x += t;
    }
    if (tid < CHUNK && (tid & 63) == 63) wsum2[tid >> 6] = x;
    __syncthreads();
    int base = b * CAP;                  // bucket-major: no global scan needed
    if (tid < CHUNK) {
        int pre = (tid >> 6) ? wsum2[0] : 0;
        int excl = x + pre - vdeg;
        lofs[tid] = excl;
        cur[tid] = 0;
        int node = b * CHUNK + tid;
        if (node < N) {
            c.row_ptr[node] = base + excl;
            c.degA[node] = vdeg;
            c.dinv[node] = rsqrtf((float)vdeg + 1.0f);
        }
    }
    __syncthreads();
    for (int i = tid; i < cnt; i += 256) {
        unsigned int p = c.temp[tb + i];
        int dl = p >> 17;
        int rank = atomicAdd(&cur[dl], 1);
        c.csr[base + lofs[dl] + rank] = (p & 0x1FFFFu) << 6;   // src byte offset
    }
}

// Shared MFMA body: A-fragments provided; B from Wt; store fp8 Hs.
__device__ __forceinline__ void mfma_tail(short8 a0, short8 a1,
                                          const unsigned short* __restrict__ Wt,
                                          unsigned char* __restrict__ Hs,
                                          int row0, int r, int q, int N) {
    short8 bfrag[4][2];
#pragma unroll
    for (int ct = 0; ct < 4; ++ct)
#pragma unroll
        for (int kb = 0; kb < 2; ++kb)
            bfrag[ct][kb] = *(const short8*)(Wt + (ct * 16 + r) * 64 + q * 8 + 32 * kb);
    f32x4 acc[4];
#pragma unroll
    for (int ct = 0; ct < 4; ++ct) {
        acc[ct] = (f32x4){0.0f, 0.0f, 0.0f, 0.0f};
        acc[ct] = __builtin_amdgcn_mfma_f32_16x16x32_bf16(a0, bfrag[ct][0], acc[ct], 0, 0, 0);
        acc[ct] = __builtin_amdgcn_mfma_f32_16x16x32_bf16(a1, bfrag[ct][1], acc[ct], 0, 0, 0);
    }
#pragma unroll
    for (int reg = 0; reg < 4; ++reg) {
        int row = row0 + q * 4 + reg;
        if (row < N) {
            size_t base = (size_t)row * 64 + r;
#pragma unroll
            for (int ct = 0; ct < 4; ++ct)
                Hs[base + ct * 16] = f2fp8(acc[ct][reg]);
        }
    }
}

// GEMM1: fp32 X in, dinv folded into A-fragment conversion.
__global__ __launch_bounds__(256) void k_gemm1(Ctx c0, Ctx c1, int nb0,
                                               const unsigned short* __restrict__ Wt,
                                               int nTiles, int N) {
    int b = blockIdx.x; Ctx c = c0;
    if (b >= nb0) { c = c1; b -= nb0; }
    int wave = threadIdx.x >> 6, lane = threadIdx.x & 63;
    int tile = b * 4 + wave;
    if (tile >= nTiles) return;
    int r = lane & 15, q = lane >> 4;
    int row0 = tile * 16;
    int row = row0 + r;
    int rr = row < N ? row : N - 1;
    float d = c.dinv[rr];
    const float* xrow = c.X + (size_t)rr * 64 + q * 8;
    short8 a0, a1;
#pragma unroll
    for (int j = 0; j < 8; ++j) a0[j] = (short)f2bf(xrow[j] * d);
#pragma unroll
    for (int j = 0; j < 8; ++j) a1[j] = (short)f2bf(xrow[32 + j] * d);
    mfma_tail(a0, a1, Wt, c.Hs, row0, r, q, N);
}

// agg block mapping: XCD-partition swizzle (graph = (blockIdx>>2)&1) when
// swz, else linear split.
__device__ __forceinline__ void agg_map(int bi, int nb0, int swz,
                                        const Ctx& c0, const Ctx& c1,
                                        Ctx& c, int& b) {
    if (swz) {
        int graph = (bi >> 2) & 1;
        b = ((bi >> 3) << 2) | (bi & 3);
        c = graph ? c1 : c0;
    } else {
        b = bi; c = c0;
        if (b >= nb0) { c = c1; b -= nb0; }
    }
}

// 8-deep dwordx2 issue/consume windows; one window = 32 slots (4 edges
// per wave-instruction: 8 subgroups x 8 lanes x 8B). slotbase
// compile-time, lim scalar (SGPR).
__device__ __forceinline__ void agg_issue8w(const unsigned char* __restrict__ Hs,
                                            unsigned int idx, int lim,
                                            int hbase, int j, unsigned int s8,
                                            uint2v* h) {
#pragma unroll
    for (int u = 0; u < 8; ++u) {
        if (4 * u >= lim) break;              // SGPR cmp -> s_cbranch
        unsigned int su = (unsigned int)__shfl((int)idx, hbase + 4 * u + j, 64);
        h[u] = *(const uint2v*)(Hs + (su | s8));
    }
}
__device__ __forceinline__ void agg_cons8w(const uint2v* h, int lim, float2v* acc) {
#pragma unroll
    for (int u = 0; u < 8; ++u) {
        if (4 * u >= lim) break;
        acc[0] += up8lo(h[u][0]); acc[1] += up8hi(h[u][0]);   // sentinel adds 0
        acc[2] += up8lo(h[u][1]); acc[3] += up8hi(h[u][1]);
    }
}

// Two node-pairs per wave, pipelined: both cold idx loads overlap; both
// pairs' first windows (32 edges) are in flight before the first wait.
// Per half: 4 subgroups x 8 lanes; lane s covers fp8 channels 8s..8s+7.
// csr holds src<<6; gather offset = su | (s*8). Invalid slots ->
// sentinel N<<6 (zeros).
__device__ __forceinline__ void agg_pair2(const unsigned char* __restrict__ Hs,
                                          const unsigned int* __restrict__ csr,
                                          int beg0, int deg0, int maxs0,
                                          int beg1, int deg1, int maxs1,
                                          int lane, unsigned int sent,
                                          float2v* acc0, float2v* acc1) {
    int hbase = lane & 32;
    int hl = lane & 31;
    int j = (hl >> 3) & 3;
    unsigned int s8 = (unsigned int)((lane & 7) * 8);
    unsigned int idx0 = (hl < deg0) ? csr[beg0 + hl] : sent;
    unsigned int idx1 = (hl < deg1) ? csr[beg1 + hl] : sent;
    int lim0 = maxs0 > 32 ? 32 : maxs0;   // scalar
    int lim1 = maxs1 > 32 ? 32 : maxs1;   // scalar
    uint2v h0[8], h1[8];
    agg_issue8w(Hs, idx0, lim0, hbase, j, s8, h0);
    agg_issue8w(Hs, idx1, lim1, hbase, j, s8, h1);
    agg_cons8w(h0, lim0, acc0);
    agg_cons8w(h1, lim1, acc1);
    // rare deep tails (deg > 32)
    for (int base = 32; base < maxs0; base += 32) {
        unsigned int idx = (base + hl < deg0) ? csr[beg0 + base + hl] : sent;
        int lim = maxs0 - base; if (lim > 32) lim = 32;
        uint2v hh[8];
        agg_issue8w(Hs, idx, lim, hbase, j, s8, hh);
        agg_cons8w(hh, lim, acc0);
    }
    for (int base = 32; base < maxs1; base += 32) {
        unsigned int idx = (base + hl < deg1) ? csr[beg1 + base + hl] : sent;
        int lim = maxs1 - base; if (lim > 32) lim = 32;
        uint2v hh[8];
        agg_issue8w(Hs, idx, lim, hbase, j, s8, hh);
        agg_cons8w(hh, lim, acc1);
    }
    // merge the half's 4 subgroups (bits 3,4); does not cross halves
#pragma unroll
    for (int k = 0; k < 4; ++k) {
        float2v o;
        o.x = __shfl_xor(acc0[k].x, 8, 64);  o.y = __shfl_xor(acc0[k].y, 8, 64);
        acc0[k] += o;
        o.x = __shfl_xor(acc0[k].x, 16, 64); o.y = __shfl_xor(acc0[k].y, 16, 64);
        acc0[k] += o;
        o.x = __shfl_xor(acc1[k].x, 8, 64);  o.y = __shfl_xor(acc1[k].y, 8, 64);
        acc1[k] += o;
        o.x = __shfl_xor(acc1[k].x, 16, 64); o.y = __shfl_xor(acc1[k].y, 16, 64);
        acc1[k] += o;
    }
}

// layer-1 + fused GEMM2: block = 16 nodes (4 waves x 2 pairs). v = dinv *
// relu(b + dinv * agg); rows staged in LDS bf16 (XOR-swizzled at
// 8-element granularity), one barrier, each wave MFMAs one 16-col tile
// of W2, stores fp8 Hs2. Hs2 sentinel row N zeroed here (aliases temp).
__global__ __launch_bounds__(256, 8) void k_agg1(Ctx c0, Ctx c1, int nb0, int swz,
                                                 const float* __restrict__ bias,
                                                 const unsigned short* __restrict__ Wt2,
                                                 int n) {
    __shared__ unsigned short As[16][64];
    Ctx c; int b;
    agg_map(blockIdx.x, nb0, swz, c0, c1, c, b);
    int wave = threadIdx.x >> 6, lane = threadIdx.x & 63;
    int h = lane >> 5;
    int nbase = b * 16 + wave * 4;
    int node0 = nbase + h;
    int node1 = nbase + 2 + h;
    int nd0 = node0 < n ? node0 : 0;
    int nd1 = node1 < n ? node1 : 0;
    int beg0 = c.row_ptr[nd0];
    int beg1 = c.row_ptr[nd1];
    int deg0 = (node0 < n) ? c.degA[nd0] : 0;
    int deg1 = (node1 < n) ? c.degA[nd1] : 0;
    int od0 = __shfl_xor(deg0, 32, 64); int m0 = deg0 > od0 ? deg0 : od0;
    int od1 = __shfl_xor(deg1, 32, 64); int m1 = deg1 > od1 ? deg1 : od1;
    int maxs0 = __builtin_amdgcn_readfirstlane(m0);
    int maxs1 = __builtin_amdgcn_readfirstlane(m1);
    if (b == 0 && threadIdx.x < 64) c.Hs2[(size_t)n * 64 + threadIdx.x] = 0;
    float2v acc0[4] = {{0.f,0.f},{0.f,0.f},{0.f,0.f},{0.f,0.f}};
    float2v acc1[4] = {{0.f,0.f},{0.f,0.f},{0.f,0.f},{0.f,0.f}};
    agg_pair2(c.Hs, c.csr, beg0, deg0, maxs0, beg1, deg1, maxs1,
              lane, (unsigned int)n << 6, acc0, acc1);
    if (((lane >> 3) & 3) == 0) {          // first subgroup of each half
        int s = lane & 7;
#pragma unroll
        for (int pr = 0; pr < 2; ++pr) {
            const float2v* ac = pr ? acc1 : acc0;
            int node = nbase + pr * 2 + h;
            ushort4 oA = {0, 0, 0, 0}, oB = {0, 0, 0, 0};
            if (node < n) {
                uint2v hv = *(const uint2v*)(c.Hs + (size_t)node * 64 + s * 8);
                float2v h0 = up8lo(hv[0]), h1 = up8hi(hv[0]);
                float2v h2 = up8lo(hv[1]), h3 = up8hi(hv[1]);
                float4 ba = *(const float4*)(bias + s * 8);
                float4 bb = *(const float4*)(bias + s * 8 + 4);
                float d = c.dinv[node];
                oA.x = f2bf(fmaxf(ba.x + d * (ac[0].x + h0.x), 0.0f) * d);
                oA.y = f2bf(fmaxf(ba.y + d * (ac[0].y + h0.y), 0.0f) * d);
                oA.z = f2bf(fmaxf(ba.z + d * (ac[1].x + h1.x), 0.0f) * d);
                oA.w = f2bf(fmaxf(ba.w + d * (ac[1].y + h1.y), 0.0f) * d);
                oB.x = f2bf(fmaxf(bb.x + d * (ac[2].x + h2.x), 0.0f) * d);
                oB.y = f2bf(fmaxf(bb.y + d * (ac[2].y + h2.y), 0.0f) * d);
                oB.z = f2bf(fmaxf(bb.z + d * (ac[3].x + h3.x), 0.0f) * d);
                oB.w = f2bf(fmaxf(bb.w + d * (ac[3].y + h3.y), 0.0f) * d);
            }
            int row = wave * 4 + pr * 2 + h;
            int col = (s * 8) ^ ((row & 7) << 3);
            *(ushort4*)(&As[row][col]) = oA;       // swizzled (8-elem blocks)
            *(ushort4*)(&As[row][col + 4]) = oB;
        }
    }
    __syncthreads();
    // fused GEMM2: wave handles col-tile ct = wave; all 16 A rows valid.
    {
        int r = lane & 15, q = lane >> 4;
        int sw = (r & 7) << 3;
        short8 a0 = *(const short8*)(&As[r][(q * 8) ^ sw]);
        short8 a1 = *(const short8*)(&As[r][(q * 8 + 32) ^ sw]);
        const unsigned short* wp = Wt2 + (wave * 16 + r) * 64 + q * 8;
        short8 b0 = *(const short8*)(wp);
        short8 b1 = *(const short8*)(wp + 32);
        f32x4 acc2 = {0.0f, 0.0f, 0.0f, 0.0f};
        acc2 = __builtin_amdgcn_mfma_f32_16x16x32_bf16(a0, b0, acc2, 0, 0, 0);
        acc2 = __builtin_amdgcn_mfma_f32_16x16x32_bf16(a1, b1, acc2, 0, 0, 0);
#pragma unroll
        for (int reg = 0; reg < 4; ++reg) {
            int l = q * 4 + reg;                     // local row 0..15
            int row = b * 16 + l;
            if (row < n)
                c.Hs2[(size_t)row * 64 + wave * 16 + r] = f2fp8(acc2[reg]);
        }
    }
}

// layer-2: block = 16 nodes; block-reduce 16 relu'd rows -> P[block, f]
// (gathers from Hs2)
__global__ __launch_bounds__(256, 8) void k_agg2(Ctx c0, Ctx c1, int nb0, int swz,
                                                 const float* __restrict__ bias, int n) {
    __shared__ float red[16 * 64];
    Ctx c; int b;
    agg_map(blockIdx.x, nb0, swz, c0, c1, c, b);
    int wave = threadIdx.x >> 6, lane = threadIdx.x & 63;
    int h = lane >> 5;
    int nbase = b * 16 + wave * 4;
    int node0 = nbase + h;
    int node1 = nbase + 2 + h;
    int nd0 = node0 < n ? node0 : 0;
    int nd1 = node1 < n ? node1 : 0;
    int beg0 = c.row_ptr[nd0];
    int beg1 = c.row_ptr[nd1];
    int deg0 = (node0 < n) ? c.degA[nd0] : 0;
    int deg1 = (node1 < n) ? c.degA[nd1] : 0;
    int od0 = __shfl_xor(deg0, 32, 64); int m0 = deg0 > od0 ? deg0 : od0;
    int od1 = __shfl_xor(deg1, 32, 64); int m1 = deg1 > od1 ? deg1 : od1;
    int maxs0 = __builtin_amdgcn_readfirstlane(m0);
    int maxs1 = __builtin_amdgcn_readfirstlane(m1);
    float2v acc0[4] = {{0.f,0.f},{0.f,0.f},{0.f,0.f},{0.f,0.f}};
    float2v acc1[4] = {{0.f,0.f},{0.f,0.f},{0.f,0.f},{0.f,0.f}};
    agg_pair2(c.Hs2, c.csr, beg0, deg0, maxs0, beg1, deg1, maxs1,
              lane, (unsigned int)n << 6, acc0, acc1);
    if (((lane >> 3) & 3) == 0) {
        int s = lane & 7;
#pragma unroll
        for (int pr = 0; pr < 2; ++pr) {
            const float2v* ac = pr ? acc1 : acc0;
            int node = nbase + pr * 2 + h;
            float4 vA = {0.f, 0.f, 0.f, 0.f}, vB = {0.f, 0.f, 0.f, 0.f};
            if (node < n) {
                uint2v hv = *(const uint2v*)(c.Hs2 + (size_t)node * 64 + s * 8);
                float2v h0 = up8lo(hv[0]), h1 = up8hi(hv[0]);
                float2v h2 = up8lo(hv[1]), h3 = up8hi(hv[1]);
                float4 ba = *(const float4*)(bias + s * 8);
                float4 bb = *(const float4*)(bias + s * 8 + 4);
                float d = c.dinv[node];
                vA.x = fmaxf(ba.x + d * (ac[0].x + h0.x), 0.0f);
                vA.y = fmaxf(ba.y + d * (ac[0].y + h0.y), 0.0f);
                vA.z = fmaxf(ba.z + d * (ac[1].x + h1.x), 0.0f);
                vA.w = fmaxf(ba.w + d * (ac[1].y + h1.y), 0.0f);
                vB.x = fmaxf(bb.x + d * (ac[2].x + h2.x), 0.0f);
                vB.y = fmaxf(bb.y + d * (ac[2].y + h2.y), 0.0f);
                vB.z = fmaxf(bb.z + d * (ac[3].x + h3.x), 0.0f);
                vB.w = fmaxf(bb.w + d * (ac[3].y + h3.y), 0.0f);
            }
            int row = wave * 4 + pr * 2 + h;
            *(float4*)(&red[row * 64 + s * 8]) = vA;
            *(float4*)(&red[row * 64 + s * 8 + 4]) = vB;
        }
    }
    __syncthreads();
    if (threadIdx.x < 64) {
        float acc16 = 0.0f;
#pragma unroll
        for (int r = 0; r < 16; ++r) acc16 += red[r * 64 + threadIdx.x];
        c.P[(size_t)b * 64 + threadIdx.x] = acc16;
    }
}

// colsum -> per-block partials in P2 (no atomics, no zero pass)
__global__ void k_colsum(Ctx c0, Ctx c1, int nb0, int rows) {
    int b = blockIdx.x; Ctx c = c0;
    if (b >= nb0) { c = c1; b -= nb0; }
    int f = threadIdx.x;  // 64
    float acc = 0.0f;
    for (int r = b; r < rows; r += nb0) acc += c.P[(size_t)r * 64 + f];
    c.P2[b * 64 + f] = acc;
}

// single-wave FC: reduce 256 partial rows, then out = fcb + (S/n) @ fcw^T
__global__ void k_fc(Ctx c0, Ctx c1, const float* __restrict__ fcw,
                     const float* __restrict__ fcb, int n) {
    Ctx c = blockIdx.x ? c1 : c0;
    __shared__ float S[64];
    int j = threadIdx.x;  // 64
    float s = 0.0f;
    for (int r = 0; r < 256; ++r) s += c.P2[r * 64 + j];
    S[j] = s;
    __syncthreads();
    float inv = 1.0f / (float)n;
    float acc = fcb[j];
#pragma unroll
    for (int k = 0; k < 64; ++k) acc += (S[k] * inv) * fcw[j * 64 + k];
    c.outp[j] = acc;
}

extern "C" void kernel_launch(void* const* d_in, const int* in_sizes, int n_in,
                              void* d_out, int out_size, void* d_ws, size_t ws_size,
                              hipStream_t stream) {
    const float* x[2]  = {(const float*)d_in[0], (const float*)d_in[1]};
    const int*   ei[2] = {(const int*)d_in[2], (const int*)d_in[3]};
    const float* W1  = (const float*)d_in[4];
    const float* b1  = (const float*)d_in[5];
    const float* W2  = (const float*)d_in[6];
    const float* b2  = (const float*)d_in[7];
    const float* fcw = (const float*)d_in[8];
    const float* fcb = (const float*)d_in[9];
    float* out = (float*)d_out;

    const int N  = in_sizes[0] / 64;
    const int E  = in_sizes[2] / 2;
    const int NF = N * 64;
    const int K  = (N + CHUNK - 1) / CHUNK;     // 782 buckets
    const int gGm  = (N + 15) / 16;             // aggregate blocks (16 nodes each)
    const int gGmP = (gGm + 3) & ~3;            // padded so swizzle stays legal
    const int nTiles = (N + 15) / 16;
    const int gMf = (nTiles + 3) / 4;
    const int gBin = (E + EPB - 1) / EPB;
    const int gK  = (K + TPB - 1) / TPB;

    auto al = [](size_t x) { return (x + 127) & ~(size_t)127; };
    size_t tempB = (size_t)K * CAP * 4;
    size_t hs2B  = (size_t)NF + 64;                    // fp8 + sentinel row N
    size_t szRegion = al(tempB > hs2B ? tempB : hs2B); // Hs2 aliases temp
    size_t szHs  = al((size_t)NF + 64);                // fp8 + sentinel row N
    size_t szCsr = al((size_t)K * CAP * 4);            // bucket-major, stride CAP
    size_t szRp  = al((size_t)N * 4);                  // beg only
    size_t szDeg = al((size_t)N * 4);
    size_t szDi  = al((size_t)N * 4);
    size_t szCu  = al((size_t)K * CPAD * 4);           // padded cursors
    size_t szP   = al((size_t)gGmP * 64 * 4);
    size_t szP2  = al((size_t)256 * 64 * 4);
    size_t setB  = szRegion + szHs + szCsr + szRp + szDeg + szDi + szCu + szP + szP2;
    size_t wtB   = 2 * al(64 * 64 * 2);
    bool batched = ws_size >= wtB + 2 * setB;

    char* base = (char*)d_ws;
    unsigned short* Wt1 = (unsigned short*)base;
    unsigned short* Wt2 = (unsigned short*)(base + al(64 * 64 * 2));

    auto mkctx = [&](int g, char* p) {
        Ctx c;
        c.X = x[g]; c.esrc = ei[g]; c.edst = ei[g] + E;
        c.temp = (unsigned int*)p; c.Hs2 = (unsigned char*)p; p += szRegion;
        c.Hs = (unsigned char*)p; p += szHs;
        c.csr = (unsigned int*)p; p += szCsr;
        c.row_ptr = (int*)p; p += szRp;
        c.degA = (int*)p; p += szDeg;
        c.dinv = (float*)p; p += szDi;
        c.cursorG = (int*)p; p += szCu;
        c.P = (float*)p; p += szP;
        c.P2 = (float*)p;
        c.outp = out + g * 64;
        return c;
    };
    char* set0 = base + wtB;
    Ctx c0 = mkctx(0, set0);
    Ctx c1 = mkctx(1, batched ? set0 + setB : set0);   // fallback: shares set0

    k_prepW2<<<2, 256, 0, stream>>>(W1, W2, Wt1, Wt2);

    auto pipe = [&](Ctx A, Ctx B, int mult) {
        int swz = (mult == 2) ? 1 : 0;   // gGmP is always %4 == 0
        k_zeroCur<<<mult * gK, TPB, 0, stream>>>(A, B, gK, K, N);
        k_binA<<<mult * gBin, 1024, 0, stream>>>(A, B, gBin, E, K);
        k_csrb<<<mult * K, 256, 0, stream>>>(A, B, K, N);
        k_gemm1<<<mult * gMf, 256, 0, stream>>>(A, B, gMf, Wt1, nTiles, N);
        k_agg1<<<mult * gGmP, 256, 0, stream>>>(A, B, gGmP, swz, b1, Wt2, N);
        k_agg2<<<mult * gGmP, 256, 0, stream>>>(A, B, gGmP, swz, b2, N);
        k_colsum<<<mult * 256, 64, 0, stream>>>(A, B, 256, gGmP);
        k_fc<<<mult, 64, 0, stream>>>(A, B, fcw, fcb, N);
    };

    if (batched) {
        pipe(c0, c1, 2);
    } else {
        pipe(c0, c0, 1);   // sequential, shared buffer set
        pipe(c1, c1, 1);
    }
}